// Round 4
// baseline (540.720 us; speedup 1.0000x reference)
//
#include <hip/hip_runtime.h>
#include <hip/hip_bf16.h>
#include <math.h>

typedef __hip_bfloat16 bf16;
typedef unsigned short u16;
#define BF(x) __bfloat162float(x)
static __device__ __forceinline__ bf16 FB(float x) { return __float2bfloat16(x); }
static __device__ __forceinline__ u16 FBu(float x) {
    bf16 b = __float2bfloat16(x);
    return *(u16*)&b;
}

typedef __attribute__((ext_vector_type(4))) float f32x4;
typedef __attribute__((ext_vector_type(8))) __bf16 bf16x8;

// Problem: B=8, H=W=64, C=128, L=4096, NH=4, HD=32, WIN=8, N=64, NW=64, M=32768.

// Wt (prepped bf16 weights) element offsets
#define O_REDW 0
#define O_QKVW 32768
#define O_PW   131072
#define O_F1W  163840
#define O_F2W  294912
#define O_LFW  425984
#define O_GFW  442368
#define O_FFW  458752
#define O_REDB 475136
#define O_QKVB 475264
#define O_PB   476032
#define O_F1B  476288
#define O_F2B  477312
#define O_LFB  477568
#define O_GFB  477696
#define O_FFB  477824
#define O_RP   477952
#define O_N1G  479752
#define O_N1B  480008
#define O_N2G  480264
#define O_N2B  480520
#define O_OW   480776
#define O_OB   481928
#define O_MW   481931
#define O_MB   483083

// Padded LDS tile geometry for VALU-written A-tiles (kills 16-way conflicts):
// row stride 36 u16 (72 B = 18 banks), chunk stride 2320 u16.
#define ROW_S 36
#define CH_S  2320

// Runtime input-dtype detection from xt (N(0,1) data). 0 = bf16, 1 = fp32.
__device__ __forceinline__ int get_mode(const void* xt) {
    const unsigned* w = (const unsigned*)xt;
    int zlo = 0, inband = 0;
    #pragma unroll
    for (int i = 0; i < 32; ++i) {
        unsigned lo = w[i] & 0xFFFFu;
        int e = (int)((lo >> 7) & 0xFF);
        zlo += (lo == 0u || lo == 0x8000u);
        inband += (e >= 100 && e <= 140);
    }
    if (zlo >= 29) return 1;
    return (inband >= 20) ? 0 : 1;
}

__device__ __forceinline__ float LD(const void* p, size_t i, int mode) {
    return mode ? ((const float*)p)[i] : BF(((const bf16*)p)[i]);
}

// async global->LDS, 16 bytes per lane
__device__ __forceinline__ void async16(const u16* g, u16* l) {
    __builtin_amdgcn_global_load_lds(
        (const __attribute__((address_space(1))) unsigned int*)g,
        (__attribute__((address_space(3))) unsigned int*)l, 16, 0, 0);
}

// ---------------------------------------------------------------------------
// Prep: transpose weights to [N][K] bf16 + convert params.
// ---------------------------------------------------------------------------
struct PrepT { const void* src; int srcOff, K, N, dstOff; };
struct Prep { PrepT d[29]; int start[30]; };

__global__ void prep_k(Prep p, bf16* __restrict__ dst, const void* __restrict__ dtp) {
    const int mode = get_mode(dtp);
    int i = blockIdx.x * 256 + threadIdx.x;
    if (i >= p.start[29]) return;
    int s = 0;
    while (p.start[s + 1] <= i) ++s;
    int e = i - p.start[s];
    float v;
    if (p.d[s].N > 0) {
        int n = e / p.d[s].K, k = e % p.d[s].K;
        v = LD(p.d[s].src, (size_t)p.d[s].srcOff + (size_t)k * p.d[s].N + n, mode);
    } else {
        v = LD(p.d[s].src, (size_t)p.d[s].srcOff + e, mode);
    }
    dst[p.d[s].dstOff + e] = FB(v);
}

// Vectorized concat: X[32768][256] = bf16([xt | hx]).  Grid-stride.
__launch_bounds__(256)
__global__ void xcat_k(const void* __restrict__ xt, const void* __restrict__ hx,
                       u16* __restrict__ X) {
    const int mode = get_mode(xt);
    const int total = 32768 * 32;            // groups of 8 elements
    for (int gidx = blockIdx.x * 256 + threadIdx.x; gidx < total;
         gidx += gridDim.x * 256) {
        int r = gidx >> 5, gi = gidx & 31;
        const void* src = (gi < 16) ? xt : hx;
        int c = (gi & 15) << 3;
        u16 outv[8];
        if (mode) {
            const float* s = (const float*)src + (size_t)r * 128 + c;
            float4 a = *(const float4*)s;
            float4 b = *(const float4*)(s + 4);
            outv[0] = FBu(a.x); outv[1] = FBu(a.y); outv[2] = FBu(a.z); outv[3] = FBu(a.w);
            outv[4] = FBu(b.x); outv[5] = FBu(b.y); outv[6] = FBu(b.z); outv[7] = FBu(b.w);
        } else {
            *(uint4*)outv = *(const uint4*)((const u16*)src + (size_t)r * 128 + c);
        }
        *(uint4*)(X + (size_t)r * 256 + (gi << 3)) = *(const uint4*)outv;
    }
}

// ---------------------------------------------------------------------------
// MFMA GEMM, 64x128 tile (grid (1,512) -> 2 blocks/CU), BK=32, double-
// buffered LDS staging: stage(k+1) is issued BEFORE compute(k), one barrier
// per K-step (T3 minimum-2-phase). EPI 3: window-reverse/roll scatter-add
// into outf. 5: fp32 store.
// ---------------------------------------------------------------------------
template <int EPI>
__launch_bounds__(256)
__global__ void gemm_mfma(const u16* __restrict__ A, const u16* __restrict__ Bt,
                          const bf16* __restrict__ bias, bf16* __restrict__ outb,
                          float* __restrict__ outf, int M, int N, int K, int shift) {
    __shared__ __align__(16) u16 Als[2][2048];   // 64 rows x 32 k
    __shared__ __align__(16) u16 Bls[2][4096];   // 128 rows x 32 k
    const int tid = threadIdx.x;
    const int wave = tid >> 6, lane = tid & 63;
    const int q = lane >> 4, lr = lane & 15;
    const int wm = (wave >> 1) << 5, wn = (wave & 1) << 6;
    const int bm = blockIdx.y << 6, bn = blockIdx.x << 7;
    const f32x4 zero = {0.f, 0.f, 0.f, 0.f};
    f32x4 acc[2][4];
    #pragma unroll
    for (int i = 0; i < 2; ++i)
        #pragma unroll
        for (int j = 0; j < 4; ++j) acc[i][j] = zero;

    const int nk = K >> 5;
    {   // prologue: stage k-tile 0 into buffer 0
        int c = tid;
        async16(A + (size_t)(bm + (c >> 2)) * K + ((c & 3) << 3), Als[0] + (c << 3));
        #pragma unroll
        for (int c2 = tid; c2 < 512; c2 += 256)
            async16(Bt + (size_t)(bn + (c2 >> 2)) * K + ((c2 & 3) << 3), Bls[0] + (c2 << 3));
    }
    __syncthreads();

    for (int i = 0; i < nk; ++i) {
        const int cur = i & 1, nxt = cur ^ 1;
        if (i + 1 < nk) {                      // issue next-tile stage FIRST
            int k1 = (i + 1) << 5;
            int c = tid;
            async16(A + (size_t)(bm + (c >> 2)) * K + k1 + ((c & 3) << 3), Als[nxt] + (c << 3));
            #pragma unroll
            for (int c2 = tid; c2 < 512; c2 += 256)
                async16(Bt + (size_t)(bn + (c2 >> 2)) * K + k1 + ((c2 & 3) << 3), Bls[nxt] + (c2 << 3));
        }
        bf16x8 af[2], bfr[4];
        #pragma unroll
        for (int t = 0; t < 2; ++t)
            af[t] = *(const bf16x8*)(Als[cur] + ((wm + (t << 4) + lr) << 5) + (q << 3));
        #pragma unroll
        for (int t = 0; t < 4; ++t)
            bfr[t] = *(const bf16x8*)(Bls[cur] + ((wn + (t << 4) + lr) << 5) + (q << 3));
        #pragma unroll
        for (int mt = 0; mt < 2; ++mt)
            #pragma unroll
            for (int nt = 0; nt < 4; ++nt)
                acc[mt][nt] = __builtin_amdgcn_mfma_f32_16x16x32_bf16(
                    af[mt], bfr[nt], acc[mt][nt], 0, 0, 0);
        __syncthreads();                        // drains next-tile stage
    }

    #pragma unroll
    for (int nt = 0; nt < 4; ++nt) {
        int col = bn + wn + (nt << 4) + lr;
        float bv = BF(bias[col]);
        #pragma unroll
        for (int mt = 0; mt < 2; ++mt) {
            int row0 = bm + wm + (mt << 4) + (q << 2);
            #pragma unroll
            for (int i = 0; i < 4; ++i) {
                int r = row0 + i;
                float v = acc[mt][nt][i] + bv;
                size_t idx = (size_t)r * N + col;
                if (EPI == 0) {
                    outb[idx] = FB(v);
                } else if (EPI == 3) {
                    int b = r >> 12, rem = r & 4095;
                    int wi = rem >> 6, n = rem & 63;
                    int hp = ((wi >> 3) << 3) + (n >> 3);
                    int wp = ((wi & 7) << 3) + (n & 7);
                    int h = (hp + shift) & 63, w = (wp + shift) & 63;
                    outf[((size_t)((b << 12) + (h << 6) + w)) * 128 + col] += v;
                } else if (EPI == 5) {
                    outf[idx] = v;
                }
            }
        }
    }
}

// ---------------------------------------------------------------------------
// Fused LN1 (+roll+window gather) + QKV GEMM. Block = 64 windowed rows,
// 512 blocks. LDS: Ach 4x[64][36] padded | Bb double-buffered 2x16KB.
// Pipeline: 6 half-K sub-tiles (nc x khalf); stage(s+1) issued before
// compute(s); stage(0) issued before the LN so it hides under LN's loads.
// ---------------------------------------------------------------------------
__launch_bounds__(256)
__global__ void qkvln_k(const float* __restrict__ g, const u16* __restrict__ wtu,
                        const bf16* __restrict__ wtb, u16* __restrict__ qkv,
                        int d, int shift) {
    __shared__ __align__(16) u16 Ach[4 * CH_S];
    __shared__ __align__(16) u16 Bb[2][8192];
    const int tid = threadIdx.x;
    const int wave = tid >> 6, lane = tid & 63;
    const int q = lane >> 4, lr = lane & 15;
    const int wm = (wave >> 1) << 5, wn = (wave & 1) << 6;
    const int bm = blockIdx.x << 6;
    const u16* Wq = wtu + O_QKVW + d * 49152;

    // prologue stage: sub-tile 0 (nc=0, khalf=0) into Bb[0]
    #pragma unroll
    for (int i = tid; i < 1024; i += 256) {
        int kc = i >> 9, c = i & 511;
        async16(Wq + (size_t)(c >> 2) * 128 + (kc << 5) + ((c & 3) << 3),
                Bb[0] + (kc << 12) + (c << 3));
    }

    // LN1 with inverse-roll gather: thread = (row = tid>>2, qtr = tid&3)
    {
        int row = tid >> 2, qtr = tid & 3;
        int r = bm + row;
        int b = r >> 12, rem = r & 4095;
        int wi = rem >> 6, n = rem & 63;
        int hp = ((wi >> 3) << 3) + (n >> 3);
        int wp = ((wi & 7) << 3) + (n & 7);
        int h = (hp + shift) & 63, w = (wp + shift) & 63;
        int src = (b << 12) + (h << 6) + w;
        const float* gr = g + (size_t)src * 128 + qtr * 32;
        float vals[32];
        float s1 = 0.f, s2 = 0.f;
        #pragma unroll
        for (int i = 0; i < 8; ++i) {
            float4 v4 = *(const float4*)(gr + i * 4);
            vals[i * 4] = v4.x; vals[i * 4 + 1] = v4.y;
            vals[i * 4 + 2] = v4.z; vals[i * 4 + 3] = v4.w;
            s1 += v4.x + v4.y + v4.z + v4.w;
            s2 += v4.x * v4.x + v4.y * v4.y + v4.z * v4.z + v4.w * v4.w;
        }
        s1 += __shfl_xor(s1, 1); s1 += __shfl_xor(s1, 2);
        s2 += __shfl_xor(s2, 1); s2 += __shfl_xor(s2, 2);
        float mu = s1 * (1.f / 128.f);
        float var = s2 * (1.f / 128.f) - mu * mu;
        float inv = rsqrtf(var + 1e-5f);
        #pragma unroll
        for (int i = 0; i < 32; ++i) {
            int c = qtr * 32 + i;
            float o = (vals[i] - mu) * inv * BF(wtb[O_N1G + d * 128 + c])
                      + BF(wtb[O_N1B + d * 128 + c]);
            Ach[qtr * CH_S + row * ROW_S + i] = FBu(o);
        }
    }
    __syncthreads();   // drains stage(0); Ach visible

    const f32x4 zero = {0.f, 0.f, 0.f, 0.f};
    f32x4 acc[2][4];
    for (int s = 0; s < 6; ++s) {
        const int nc = s >> 1, kh = s & 1;
        const int bsel = s & 1;
        if (s < 5) {   // issue next sub-tile stage first
            int t = s + 1, nct = t >> 1, kht = t & 1;
            const u16* Bg = Wq + nct * 16384;
            #pragma unroll
            for (int i = tid; i < 1024; i += 256) {
                int kc = i >> 9, c = i & 511;
                async16(Bg + (size_t)(c >> 2) * 128 + (kht << 6) + (kc << 5) + ((c & 3) << 3),
                        Bb[t & 1] + (kc << 12) + (c << 3));
            }
        }
        if (kh == 0) {
            #pragma unroll
            for (int i = 0; i < 2; ++i)
                #pragma unroll
                for (int j = 0; j < 4; ++j) acc[i][j] = zero;
        }
        #pragma unroll
        for (int kc = 0; kc < 2; ++kc) {
            bf16x8 af[2], bfr[4];
            #pragma unroll
            for (int t = 0; t < 2; ++t)
                af[t] = *(const bf16x8*)(Ach + (2 * kh + kc) * CH_S + (wm + (t << 4) + lr) * ROW_S + (q << 3));
            #pragma unroll
            for (int t = 0; t < 4; ++t)
                bfr[t] = *(const bf16x8*)(Bb[bsel] + (kc << 12) + ((wn + (t << 4) + lr) << 5) + (q << 3));
            #pragma unroll
            for (int mt = 0; mt < 2; ++mt)
                #pragma unroll
                for (int nt = 0; nt < 4; ++nt)
                    acc[mt][nt] = __builtin_amdgcn_mfma_f32_16x16x32_bf16(
                        af[mt], bfr[nt], acc[mt][nt], 0, 0, 0);
        }
        if (kh == 1) {   // epilogue for this nc
            #pragma unroll
            for (int nt = 0; nt < 4; ++nt) {
                int col = wn + (nt << 4) + lr;
                float bv = BF(wtb[O_QKVB + d * 384 + nc * 128 + col]);
                #pragma unroll
                for (int mt = 0; mt < 2; ++mt) {
                    #pragma unroll
                    for (int i = 0; i < 4; ++i) {
                        int r = bm + wm + (mt << 4) + (q << 2) + i;
                        qkv[(size_t)r * 384 + nc * 128 + col] = FBu(acc[mt][nt][i] + bv);
                    }
                }
            }
        }
        if (s < 5) __syncthreads();   // drains stage(s+1); frees Bb[bsel]
    }
}

// ---------------------------------------------------------------------------
// Windowed MFMA attention: block = one window, wave = one head. Zero
// barriers (all LDS slices are wave-private). QK^T and PV on matrix cores
// (16+16 mfma_16x16x32_bf16 per wave); softmax in-register with 16-lane
// shfl_xor row reductions. Fragment math identical to gemm_mfma
// (A row=lr, k=q8*8; C row=q8*4+i, col=lr).
// ---------------------------------------------------------------------------
__launch_bounds__(256, 2)
__global__ void attn_k(const u16* __restrict__ qkv, const bf16* __restrict__ rp,
                       u16* __restrict__ outp, int shift) {
    __shared__ __align__(16) u16 vT[4][32][72];    // V^T per head (padded)
    __shared__ __align__(16) u16 pbuf[4][64][72];  // P bf16 per head (padded)
    const int wq = blockIdx.x;
    const int head = threadIdx.x >> 6;
    const int lane = threadIdx.x & 63;
    const int q8 = lane >> 4, lr = lane & 15;
    const size_t base = (size_t)wq * 64;
    const f32x4 zero = {0.f, 0.f, 0.f, 0.f};

    // stage V^T: thread=m-row, 4x bf16x8 global loads -> scattered u16 writes
    #pragma unroll
    for (int j = 0; j < 4; ++j) {
        bf16x8 vv = *(const bf16x8*)(qkv + (base + lane) * 384 + 256 + head * 32 + j * 8);
        #pragma unroll
        for (int e = 0; e < 8; ++e) vT[head][j * 8 + e][lane] = ((const u16*)&vv)[e];
    }

    // Q/K fragments direct from global (16B contiguous), S = Q K^T
    bf16x8 af[4], bfk[4];
    #pragma unroll
    for (int t = 0; t < 4; ++t) {
        af[t]  = *(const bf16x8*)(qkv + (base + t * 16 + lr) * 384 + head * 32 + q8 * 8);
        bfk[t] = *(const bf16x8*)(qkv + (base + t * 16 + lr) * 384 + 128 + head * 32 + q8 * 8);
    }
    f32x4 accs[4][4];
    #pragma unroll
    for (int rt = 0; rt < 4; ++rt)
        #pragma unroll
        for (int ct = 0; ct < 4; ++ct) accs[rt][ct] = zero;
    #pragma unroll
    for (int rt = 0; rt < 4; ++rt)
        #pragma unroll
        for (int ct = 0; ct < 4; ++ct)
            accs[rt][ct] = __builtin_amdgcn_mfma_f32_16x16x32_bf16(
                af[rt], bfk[ct], accs[rt][ct], 0, 0, 0);

    // scale + rel-pos bias + region mask + softmax + normalized bf16 P -> LDS
    const int wloc = wq & 63;
    const int wh = (wloc >> 3) << 3, wwb = (wloc & 7) << 3;
    #pragma unroll
    for (int rt = 0; rt < 4; ++rt) {
        #pragma unroll
        for (int i = 0; i < 4; ++i) {
            int r = rt * 16 + q8 * 4 + i;
            int ti = r >> 3, tj = r & 7;
            int regt = 0;
            if (shift) {
                int hp = wh + ti, wp = wwb + tj;
                int rh = hp < 56 ? 0 : (hp < 60 ? 1 : 2);
                int rw = wp < 56 ? 0 : (wp < 60 ? 1 : 2);
                regt = rh * 3 + rw;
            }
            float sv[4];
            float mx = -1e30f;
            #pragma unroll
            for (int ct = 0; ct < 4; ++ct) {
                int m = ct * 16 + lr;
                float a = accs[rt][ct][i] * 0.17677669529663687f;
                int idx = (ti - (m >> 3) + 7) * 15 + (tj - (m & 7) + 7);
                a += BF(rp[idx * 4 + head]);
                if (shift) {
                    int hp = wh + (m >> 3), wp = wwb + (m & 7);
                    int rh = hp < 56 ? 0 : (hp < 60 ? 1 : 2);
                    int rw = wp < 56 ? 0 : (wp < 60 ? 1 : 2);
                    if (regt != rh * 3 + rw) a -= 100.f;
                }
                sv[ct] = a;
                mx = fmaxf(mx, a);
            }
            mx = fmaxf(mx, __shfl_xor(mx, 1));
            mx = fmaxf(mx, __shfl_xor(mx, 2));
            mx = fmaxf(mx, __shfl_xor(mx, 4));
            mx = fmaxf(mx, __shfl_xor(mx, 8));
            float l = 0.f;
            #pragma unroll
            for (int ct = 0; ct < 4; ++ct) { sv[ct] = expf(sv[ct] - mx); l += sv[ct]; }
            l += __shfl_xor(l, 1); l += __shfl_xor(l, 2);
            l += __shfl_xor(l, 4); l += __shfl_xor(l, 8);
            float inv = 1.f / l;
            #pragma unroll
            for (int ct = 0; ct < 4; ++ct)
                pbuf[head][r][ct * 16 + lr] = FBu(sv[ct] * inv);
        }
    }

    // PV: O = P @ V  (A from pbuf, B from vT; both 16B-aligned b128 reads)
    f32x4 acco[4][2];
    #pragma unroll
    for (int rt = 0; rt < 4; ++rt) { acco[rt][0] = zero; acco[rt][1] = zero; }
    #pragma unroll
    for (int mh = 0; mh < 2; ++mh) {
        bf16x8 vb[2];
        #pragma unroll
        for (int dt = 0; dt < 2; ++dt)
            vb[dt] = *(const bf16x8*)(&vT[head][dt * 16 + lr][mh * 32 + q8 * 8]);
        #pragma unroll
        for (int rt = 0; rt < 4; ++rt) {
            bf16x8 pa = *(const bf16x8*)(&pbuf[head][rt * 16 + lr][mh * 32 + q8 * 8]);
            #pragma unroll
            for (int dt = 0; dt < 2; ++dt)
                acco[rt][dt] = __builtin_amdgcn_mfma_f32_16x16x32_bf16(
                    pa, vb[dt], acco[rt][dt], 0, 0, 0);
        }
    }

    // store O rows (already normalized)
    #pragma unroll
    for (int rt = 0; rt < 4; ++rt)
        #pragma unroll
        for (int dt = 0; dt < 2; ++dt)
            #pragma unroll
            for (int i = 0; i < 4; ++i) {
                int r = rt * 16 + q8 * 4 + i;
                outp[(base + r) * 128 + head * 32 + dt * 16 + lr] = FBu(acco[rt][dt][i]);
            }
}

// ---------------------------------------------------------------------------
// Fused MLP: LN2 + f1 + GELU + f2 + residual into g (+ bf16 copy to gbf).
// Block = 64 rows, 512 blocks. LDS: Ach | bufB1 16KB | bufB2 16KB | buf2.
// Pipeline: stage B1(0) before LN; per h: issue B2(h), compute MFMA1+GELU,
// barrier, issue B1(h+1), compute MFMA2, barrier. 2 barriers/h,
// stage latency hidden under compute.
// ---------------------------------------------------------------------------
__launch_bounds__(256)
__global__ void mlp_k(float* __restrict__ g, bf16* __restrict__ gbf,
                      const u16* __restrict__ wtu, const bf16* __restrict__ wtb,
                      int d) {
    __shared__ __align__(16) u16 Ach[4 * CH_S];
    __shared__ __align__(16) u16 bufB1[8192];
    __shared__ __align__(16) u16 bufB2[8192];
    __shared__ __align__(16) u16 buf2[2 * CH_S];
    const int tid = threadIdx.x;
    const int wave = tid >> 6, lane = tid & 63;
    const int q = lane >> 4, lr = lane & 15;
    const int wm = (wave >> 1) << 5;   // 0 / 32 (row split)
    const int wn0 = (wave & 1) << 5;   // stage1: 32-hcol split
    const int wn = (wave & 1) << 6;    // stage2: 64-ncol split
    const int bm = blockIdx.x << 6;

    // prologue stage: B1 chunk h=0 (hides under LN's global loads)
    {
        const u16* B1g = wtu + O_F1W + d * 65536;
        #pragma unroll
        for (int i = tid; i < 1024; i += 256) {
            int kc = i >> 8, c = i & 255;
            async16(B1g + (c >> 2) * 128 + (kc << 5) + ((c & 3) << 3),
                    bufB1 + (kc << 11) + (c << 3));
        }
    }

    // LN2: thread = (row = tid>>2, qtr = tid&3)
    {
        int row = tid >> 2, qtr = tid & 3;
        const float* gr = g + (size_t)(bm + row) * 128 + qtr * 32;
        float vals[32];
        float s1 = 0.f, s2 = 0.f;
        #pragma unroll
        for (int i = 0; i < 8; ++i) {
            float4 v4 = *(const float4*)(gr + i * 4);
            vals[i * 4] = v4.x; vals[i * 4 + 1] = v4.y;
            vals[i * 4 + 2] = v4.z; vals[i * 4 + 3] = v4.w;
            s1 += v4.x + v4.y + v4.z + v4.w;
            s2 += v4.x * v4.x + v4.y * v4.y + v4.z * v4.z + v4.w * v4.w;
        }
        s1 += __shfl_xor(s1, 1); s1 += __shfl_xor(s1, 2);
        s2 += __shfl_xor(s2, 1); s2 += __shfl_xor(s2, 2);
        float mu = s1 * (1.f / 128.f);
        float var = s2 * (1.f / 128.f) - mu * mu;
        float inv = rsqrtf(var + 1e-5f);
        #pragma unroll
        for (int i = 0; i < 32; ++i) {
            int c = qtr * 32 + i;
            float o = (vals[i] - mu) * inv * BF(wtb[O_N2G + d * 128 + c])
                      + BF(wtb[O_N2B + d * 128 + c]);
            Ach[qtr * CH_S + row * ROW_S + i] = FBu(o);
        }
    }
    __syncthreads();   // drains B1(0); Ach visible

    const f32x4 zero = {0.f, 0.f, 0.f, 0.f};
    f32x4 acc2[2][4];
    #pragma unroll
    for (int i = 0; i < 2; ++i)
        #pragma unroll
        for (int j = 0; j < 4; ++j) acc2[i][j] = zero;

    for (int h = 0; h < 8; ++h) {
        // issue B2(h) stage first (hides under MFMA1 + GELU)
        {
            const u16* B2g = wtu + O_F2W + d * 65536 + h * 64;
            #pragma unroll
            for (int i = tid; i < 1024; i += 256) {
                int kc = i >> 9, c = i & 511;
                async16(B2g + (size_t)(c >> 2) * 512 + (kc << 5) + ((c & 3) << 3),
                        bufB2 + (kc << 12) + (c << 3));
            }
        }
        // MFMA1 from Ach x bufB1 (B1(h), ready from previous barrier)
        f32x4 acc1[2][2];
        #pragma unroll
        for (int i = 0; i < 2; ++i) { acc1[i][0] = zero; acc1[i][1] = zero; }
        #pragma unroll
        for (int k0 = 0; k0 < 4; ++k0) {
            bf16x8 af[2], bfr[2];
            #pragma unroll
            for (int t = 0; t < 2; ++t) {
                af[t]  = *(const bf16x8*)(Ach + k0 * CH_S + (wm + (t << 4) + lr) * ROW_S + (q << 3));
                bfr[t] = *(const bf16x8*)(bufB1 + (k0 << 11) + ((wn0 + (t << 4) + lr) << 5) + (q << 3));
            }
            #pragma unroll
            for (int mt = 0; mt < 2; ++mt)
                #pragma unroll
                for (int nt = 0; nt < 2; ++nt)
                    acc1[mt][nt] = __builtin_amdgcn_mfma_f32_16x16x32_bf16(
                        af[mt], bfr[nt], acc1[mt][nt], 0, 0, 0);
        }
        // GELU -> hidden chunks (padded) in buf2
        #pragma unroll
        for (int nt = 0; nt < 2; ++nt) {
            int c = wn0 + (nt << 4) + lr;
            float hb = BF(wtb[O_F1B + d * 512 + h * 64 + c]);
            #pragma unroll
            for (int mt = 0; mt < 2; ++mt) {
                #pragma unroll
                for (int i = 0; i < 4; ++i) {
                    int r = wm + (mt << 4) + (q << 2) + i;
                    float v = acc1[mt][nt][i] + hb;
                    float ge = 0.5f * v * (1.0f + erff(v * 0.70710678118654752f));
                    buf2[(c >> 5) * CH_S + r * ROW_S + (c & 31)] = FBu(ge);
                }
            }
        }
        __syncthreads();   // drains B2(h); buf2 visible; bufB1 free
        // issue B1(h+1) stage (hides under MFMA2)
        if (h < 7) {
            const u16* B1g = wtu + O_F1W + d * 65536 + (h + 1) * 8192;
            #pragma unroll
            for (int i = tid; i < 1024; i += 256) {
                int kc = i >> 8, c = i & 255;
                async16(B1g + (c >> 2) * 128 + (kc << 5) + ((c & 3) << 3),
                        bufB1 + (kc << 11) + (c << 3));
            }
        }
        // MFMA2 from buf2 x bufB2
        #pragma unroll
        for (int kc = 0; kc < 2; ++kc) {
            bf16x8 ah[2], b2[4];
            #pragma unroll
            for (int t = 0; t < 2; ++t)
                ah[t] = *(const bf16x8*)(buf2 + kc * CH_S + (wm + (t << 4) + lr) * ROW_S + (q << 3));
            #pragma unroll
            for (int t = 0; t < 4; ++t)
                b2[t] = *(const bf16x8*)(bufB2 + (kc << 12) + ((wn + (t << 4) + lr) << 5) + (q << 3));
            #pragma unroll
            for (int mt = 0; mt < 2; ++mt)
                #pragma unroll
                for (int nt = 0; nt < 4; ++nt)
                    acc2[mt][nt] = __builtin_amdgcn_mfma_f32_16x16x32_bf16(
                        ah[mt], b2[nt], acc2[mt][nt], 0, 0, 0);
        }
        __syncthreads();   // drains B1(h+1); bufB2/buf2 free
    }
    #pragma unroll
    for (int nt = 0; nt < 4; ++nt) {
        int col = wn + (nt << 4) + lr;
        float bv = BF(wtb[O_F2B + d * 128 + col]);
        #pragma unroll
        for (int mt = 0; mt < 2; ++mt) {
            #pragma unroll
            for (int i = 0; i < 4; ++i) {
                int r = bm + wm + (mt << 4) + (q << 2) + i;
                size_t idx = (size_t)r * 128 + col;
                float nv = g[idx] + acc2[mt][nt][i] + bv;
                g[idx] = nv;
                gbf[idx] = FB(nv);
            }
        }
    }
}

// ---------------------------------------------------------------------------
// Fused fusion chain + LSTM gate -> out. 64-row tiles, 512 blocks (2/CU).
// GEMM operands loaded directly from global. Only the ReLU intermediate
// lives in LDS (padded ROW_S layout). 2 barriers total.
// ---------------------------------------------------------------------------
__launch_bounds__(256, 2)
__global__ void fuse3_k(const u16* __restrict__ Aloc, const u16* __restrict__ Ag,
                        const u16* __restrict__ wtu, const bf16* __restrict__ wtb,
                        const void* __restrict__ cx, void* __restrict__ out,
                        const void* __restrict__ dtp) {
    __shared__ __align__(16) u16 relb[4 * CH_S];
    const int mode = get_mode(dtp);
    const int tid = threadIdx.x;
    const int wave = tid >> 6, lane = tid & 63;
    const int q = lane >> 4, lr = lane & 15;
    const int wm = (wave >> 1) << 5, wn = (wave & 1) << 6;
    const int bm = blockIdx.x << 6;
    const f32x4 zero = {0.f, 0.f, 0.f, 0.f};
    f32x4 acc1[2][4], acc2[2][4];
    #pragma unroll
    for (int i = 0; i < 2; ++i)
        #pragma unroll
        for (int j = 0; j < 4; ++j) { acc1[i][j] = zero; acc2[i][j] = zero; }

    #pragma unroll
    for (int k0 = 0; k0 < 4; ++k0) {
        bf16x8 al[2], ag[2], blf[4], bgf[4];
        #pragma unroll
        for (int t = 0; t < 2; ++t) {
            size_t off = (size_t)(bm + wm + (t << 4) + lr) * 128 + (k0 << 5) + (q << 3);
            al[t] = *(const bf16x8*)(Aloc + off);
            ag[t] = *(const bf16x8*)(Ag + off);
        }
        #pragma unroll
        for (int t = 0; t < 4; ++t) {
            int woff = ((wn + (t << 4) + lr) << 7) + (k0 << 5) + (q << 3);
            blf[t] = *(const bf16x8*)(wtu + O_LFW + woff);
            bgf[t] = *(const bf16x8*)(wtu + O_GFW + woff);
        }
        #pragma unroll
        for (int mt = 0; mt < 2; ++mt)
            #pragma unroll
            for (int nt = 0; nt < 4; ++nt) {
                acc1[mt][nt] = __builtin_amdgcn_mfma_f32_16x16x32_bf16(
                    al[mt], blf[nt], acc1[mt][nt], 0, 0, 0);
                acc2[mt][nt] = __builtin_amdgcn_mfma_f32_16x16x32_bf16(
                    ag[mt], bgf[nt], acc2[mt][nt], 0, 0, 0);
            }
    }
    // relu((local@lf + lfb) * (g@gf + gfb)) -> padded LDS
    #pragma unroll
    for (int nt = 0; nt < 4; ++nt) {
        int c = wn + (nt << 4) + lr;
        float lfb = BF(wtb[O_LFB + c]);
        float gfb = BF(wtb[O_GFB + c]);
        #pragma unroll
        for (int mt = 0; mt < 2; ++mt) {
            #pragma unroll
            for (int i = 0; i < 4; ++i) {
                int r = wm + (mt << 4) + (q << 2) + i;
                float t1 = acc1[mt][nt][i] + lfb;
                float t2 = acc2[mt][nt][i] + gfb;
                float rel = t1 * t2;
                relb[(c >> 5) * CH_S + r * ROW_S + (c & 31)] = FBu(rel > 0.f ? rel : 0.f);
            }
        }
    }
    __syncthreads();
    f32x4 acc3[2][4];
    #pragma unroll
    for (int i = 0; i < 2; ++i)
        #pragma unroll
        for (int j = 0; j < 4; ++j) acc3[i][j] = zero;
    #pragma unroll
    for (int k0 = 0; k0 < 4; ++k0) {
        bf16x8 ar[2], bff[4];
        #pragma unroll
        for (int t = 0; t < 2; ++t)
            ar[t] = *(const bf16x8*)(relb + k0 * CH_S + (wm + (t << 4) + lr) * ROW_S + (q << 3));
        #pragma unroll
        for (int t = 0; t < 4; ++t)
            bff[t] = *(const bf16x8*)(wtu + O_FFW + ((wn + (t << 4) + lr) << 7) + (k0 << 5) + (q << 3));
        #pragma unroll
        for (int mt = 0; mt < 2; ++mt)
            #pragma unroll
            for (int nt = 0; nt < 4; ++nt)
                acc3[mt][nt] = __builtin_amdgcn_mfma_f32_16x16x32_bf16(
                    ar[mt], bff[nt], acc3[mt][nt], 0, 0, 0);
    }
    // LSTM gating epilogue
    #pragma unroll
    for (int nt = 0; nt < 4; ++nt) {
        int col = wn + (nt << 4) + lr;
        float ffb = BF(wtb[O_FFB + col]);
        #pragma unroll
        for (int mt = 0; mt < 2; ++mt) {
            #pragma unroll
            for (int i = 0; i < 4; ++i) {
                int r = bm + wm + (mt << 4) + (q << 2) + i;
                size_t idx = (size_t)r * 128 + col;
                float v = acc3[mt][nt][i] + ffb;
                float gate = 1.f / (1.f + expf(-v));
                float cell = tanhf(v);
                float cy = gate * (LD(cx, idx, mode) + cell);
                float hy = gate * tanhf(cy);
                if (mode) ((float*)out)[idx] = hy;
                else      ((bf16*)out)[idx] = FB(hy);
            }
        }
    }
}

// ---------------------------------------------------------------------------
// Deformable conv1d, stage 1: offset/mask conv. One WAVE per output position.
// ---------------------------------------------------------------------------
__launch_bounds__(256)
__global__ void offmask_k(const void* __restrict__ xt, const bf16* __restrict__ wtb,
                          float4* __restrict__ om) {
    const int mode = get_mode(xt);
    const int wave = threadIdx.x >> 6, lane = threadIdx.x & 63;
    const int gl = blockIdx.x * 4 + wave;
    const int b = gl >> 12, l = gl & 4095;
    float wo[3][3][2], wmk[3][3][2];
    #pragma unroll
    for (int k = 0; k < 3; ++k)
        #pragma unroll
        for (int j = 0; j < 3; ++j) {
            wo[k][j][0]  = BF(wtb[O_OW + (k * 128 + lane) * 3 + j]);
            wo[k][j][1]  = BF(wtb[O_OW + (k * 128 + lane + 64) * 3 + j]);
            wmk[k][j][0] = BF(wtb[O_MW + (k * 128 + lane) * 3 + j]);
            wmk[k][j][1] = BF(wtb[O_MW + (k * 128 + lane + 64) * 3 + j]);
        }
    float a6[6] = {};
    #pragma unroll
    for (int j = 0; j < 3; ++j) {
        int row = l + j - 1;
        if (row >= 0 && row < 4096) {
            size_t base = ((size_t)(b << 12) + row) * 128;
            float x0 = LD(xt, base + lane, mode);
            float x1 = LD(xt, base + lane + 64, mode);
            #pragma unroll
            for (int k = 0; k < 3; ++k) {
                a6[k]     += x0 * wo[k][j][0]  + x1 * wo[k][j][1];
                a6[3 + k] += x0 * wmk[k][j][0] + x1 * wmk[k][j][1];
            }
        }
    }
    #pragma unroll
    for (int off = 32; off > 0; off >>= 1)
        #pragma unroll
        for (int k = 0; k < 6; ++k) a6[k] += __shfl_down(a6[k], off);
    if (lane == 0) {
        #pragma unroll
        for (int k = 0; k < 3; ++k) {
            float off = a6[k] + BF(wtb[O_OB + k]);
            float pos = fminf(fmaxf((float)l + off, 0.f), 4095.f);
            float fpf = floorf(pos);
            float mv = a6[3 + k] + BF(wtb[O_MB + k]);
            float mk = 1.f / (1.f + expf(-mv));
            om[(size_t)gl * 3 + k] = make_float4(fpf, pos - fpf, mk, 0.f);
        }
    }
}

// ---------------------------------------------------------------------------
// Deformable conv1d, stage 2: sampling + transpose to (B,C,L) bf16.
// ---------------------------------------------------------------------------
__launch_bounds__(512)
__global__ void sample_k(const void* __restrict__ xt, const float4* __restrict__ om,
                         bf16* __restrict__ outL) {
    __shared__ __align__(16) u16 ot[128 * 72];
    const int mode = get_mode(xt);
    const int tid = threadIdx.x;
    const int b = blockIdx.x >> 6;
    const int l0 = (blockIdx.x & 63) << 6;
    const int c = tid & 127, lh = tid >> 7;
    for (int it = 0; it < 16; ++it) {
        int l_loc = lh * 16 + it;
        size_t gl = (size_t)(b << 12) + l0 + l_loc;
        float o = 0.f;
        #pragma unroll
        for (int k = 0; k < 3; ++k) {
            float4 v = om[gl * 3 + k];
            int fp = (int)v.x;
            int cp = fp + 1 > 4095 ? 4095 : fp + 1;
            float al = v.y, mk = v.z;
            float xf = LD(xt, ((size_t)(b << 12) + fp) * 128 + c, mode);
            float xc = LD(xt, ((size_t)(b << 12) + cp) * 128 + c, mode);
            o += (xf * (1.f - al) + xc * al) * mk;
        }
        ot[c * 72 + l_loc] = FBu(o);
    }
    __syncthreads();
    #pragma unroll
    for (int pass = 0; pass < 2; ++pass) {
        int cc = pass * 64 + (tid >> 3);
        int oo = tid & 7;
        const uint4 v = *(const uint4*)(ot + cc * 72 + oo * 8);
        *(uint4*)(outL + (size_t)b * 524288 + (size_t)cc * 4096 + l0 + oo * 8) = v;
    }
}

extern "C" void kernel_launch(void* const* d_in, const int* in_sizes, int n_in,
                              void* d_out, int out_size, void* d_ws, size_t ws_size,
                              hipStream_t stream) {
    (void)out_size; (void)ws_size;
    int I[28] = {0,1,2,3,4,5,6,7,8,9,10,11,12,13,14,15,16,17,18,19,20,21,22,23,24,25,26,27};
    if (n_in >= 28 && in_sizes[7] != 98304 && in_sizes[23] == 98304 && in_sizes[26] == 1800) {
        int alt[28] = {27, 9, 0, 25, 24, 15, 14, 23, 22, 26, 21, 20, 17, 16,
                       2, 1, 4, 3, 19, 18, 13, 12, 11, 10, 8, 7, 6, 5};
        for (int i = 0; i < 28; ++i) I[i] = alt[i];
    }
    const void* xt = d_in[I[0]];
    const void* hx = d_in[I[1]];
    const void* cx = d_in[I[2]];

    char* wsb = (char*)d_ws;
    float* g    = (float*)wsb;                    // fp32 residual [0,16M)
    u16*   Abf  = (u16*)(wsb + 16777216);         // bf16(g)
    u16*   Bbf  = (u16*)(wsb + 25165824);         // Xcat / qkv
    u16*   Cbf  = (u16*)(wsb + 50331648);         // attn-out / local
    bf16*  wtb  = (bf16*)(wsb + 58720256);
    u16*   wtu  = (u16*)wtb;
    float4* om  = (float4*)(wsb + 25165824);      // reuses Bbf after last attn

    Prep p;
    PrepT descs[29] = {
        {d_in[I[3]],  0,     256, 128, O_REDW},
        {d_in[I[7]],  0,     128, 384, O_QKVW},
        {d_in[I[7]],  49152, 128, 384, O_QKVW + 49152},
        {d_in[I[10]], 0,     128, 128, O_PW},
        {d_in[I[10]], 16384, 128, 128, O_PW + 16384},
        {d_in[I[14]], 0,     128, 512, O_F1W},
        {d_in[I[14]], 65536, 128, 512, O_F1W + 65536},
        {d_in[I[16]], 0,     512, 128, O_F2W},
        {d_in[I[16]], 65536, 512, 128, O_F2W + 65536},
        {d_in[I[22]], 0,     128, 128, O_LFW},
        {d_in[I[24]], 0,     128, 128, O_GFW},
        {d_in[I[26]], 0,     128, 128, O_FFW},
        {d_in[I[4]],  0,  128, 0, O_REDB},
        {d_in[I[8]],  0,  768, 0, O_QKVB},
        {d_in[I[11]], 0,  256, 0, O_PB},
        {d_in[I[15]], 0, 1024, 0, O_F1B},
        {d_in[I[17]], 0,  256, 0, O_F2B},
        {d_in[I[23]], 0,  128, 0, O_LFB},
        {d_in[I[25]], 0,  128, 0, O_GFB},
        {d_in[I[27]], 0,  128, 0, O_FFB},
        {d_in[I[9]],  0, 1800, 0, O_RP},
        {d_in[I[5]],  0,  256, 0, O_N1G},
        {d_in[I[6]],  0,  256, 0, O_N1B},
        {d_in[I[12]], 0,  256, 0, O_N2G},
        {d_in[I[13]], 0,  256, 0, O_N2B},
        {d_in[I[18]], 0, 1152, 0, O_OW},
        {d_in[I[19]], 0,    3, 0, O_OB},
        {d_in[I[20]], 0, 1152, 0, O_MW},
        {d_in[I[21]], 0,    3, 0, O_MB},
    };
    int cum = 0;
    for (int i = 0; i < 29; ++i) {
        p.d[i] = descs[i];
        p.start[i] = cum;
        cum += (descs[i].N > 0) ? descs[i].K * descs[i].N : descs[i].K;
    }
    p.start[29] = cum;

    prep_k<<<(cum + 255) / 256, 256, 0, stream>>>(p, wtb, xt);
    xcat_k<<<1024, 256, 0, stream>>>(xt, hx, Bbf);

    // g = Xcat @ red_w + red_b (fp32)
    gemm_mfma<5><<<dim3(1, 512), 256, 0, stream>>>(Bbf, wtu + O_REDW, wtb + O_REDB,
                                                   nullptr, g, 32768, 128, 256, 0);

    for (int d = 0; d < 2; ++d) {
        int shift = d ? 4 : 0;
        qkvln_k<<<512, 256, 0, stream>>>(g, wtu, wtb, Bbf, d, shift);
        attn_k<<<512, 256, 0, stream>>>(Bbf, wtb + O_RP + d * 900, Cbf, shift);
        gemm_mfma<3><<<dim3(1, 512), 256, 0, stream>>>(Cbf, wtu + O_PW + d * 16384,
                                                       wtb + O_PB + d * 128, nullptr, g,
                                                       32768, 128, 128, shift);
        mlp_k<<<512, 256, 0, stream>>>(g, (bf16*)Abf, wtu, wtb, d);
    }

    // local branch: offset/mask conv (wave-per-l), then sampling -> Cbf (B,C,L)
    offmask_k<<<8192, 256, 0, stream>>>(xt, wtb, om);
    sample_k<<<512, 512, 0, stream>>>(xt, om, (bf16*)Cbf);
    // fused fusion chain + LSTM -> out
    fuse3_k<<<512, 256, 0, stream>>>(Cbf, Abf, wtu, wtb, cx, d_out, xt);
}

// Round 5
// 404.937 us; speedup vs baseline: 1.3353x; 1.3353x over previous
//
#include <hip/hip_runtime.h>
#include <hip/hip_bf16.h>
#include <math.h>

typedef __hip_bfloat16 bf16;
typedef unsigned short u16;
#define BF(x) __bfloat162float(x)
static __device__ __forceinline__ bf16 FB(float x) { return __float2bfloat16(x); }
static __device__ __forceinline__ u16 FBu(float x) {
    bf16 b = __float2bfloat16(x);
    return *(u16*)&b;
}

typedef __attribute__((ext_vector_type(4))) float f32x4;
typedef __attribute__((ext_vector_type(8))) __bf16 bf16x8;

// Problem: B=8, H=W=64, C=128, L=4096, NH=4, HD=32, WIN=8, N=64, NW=64, M=32768.

// Wt (prepped bf16 weights) element offsets
#define O_REDW 0
#define O_QKVW 32768
#define O_PW   131072
#define O_F1W  163840
#define O_F2W  294912
#define O_LFW  425984
#define O_GFW  442368
#define O_FFW  458752
#define O_REDB 475136
#define O_QKVB 475264
#define O_PB   476032
#define O_F1B  476288
#define O_F2B  477312
#define O_LFB  477568
#define O_GFB  477696
#define O_FFB  477824
#define O_RP   477952
#define O_N1G  479752
#define O_N1B  480008
#define O_N2G  480264
#define O_N2B  480520
#define O_OW   480776
#define O_OB   481928
#define O_MW   481931
#define O_MB   483083

// Padded LDS tile geometry for VALU-written A-tiles (kills 16-way conflicts):
// row stride 36 u16 (72 B = 18 banks), chunk stride 2320 u16 (64-row chunks).
#define ROW_S 36
#define CH_S  2320
// 32-row chunk variant (fuse3): 32*36 + 16 skew
#define CH32_S 1168

// Runtime input-dtype detection from xt (N(0,1) data). 0 = bf16, 1 = fp32.
__device__ __forceinline__ int get_mode(const void* xt) {
    const unsigned* w = (const unsigned*)xt;
    int zlo = 0, inband = 0;
    #pragma unroll
    for (int i = 0; i < 32; ++i) {
        unsigned lo = w[i] & 0xFFFFu;
        int e = (int)((lo >> 7) & 0xFF);
        zlo += (lo == 0u || lo == 0x8000u);
        inband += (e >= 100 && e <= 140);
    }
    if (zlo >= 29) return 1;
    return (inband >= 20) ? 0 : 1;
}

__device__ __forceinline__ float LD(const void* p, size_t i, int mode) {
    return mode ? ((const float*)p)[i] : BF(((const bf16*)p)[i]);
}

// async global->LDS, 16 bytes per lane
__device__ __forceinline__ void async16(const u16* g, u16* l) {
    __builtin_amdgcn_global_load_lds(
        (const __attribute__((address_space(1))) unsigned int*)g,
        (__attribute__((address_space(3))) unsigned int*)l, 16, 0, 0);
}

// ---------------------------------------------------------------------------
// Prep: transpose weights to [N][K] bf16 + convert params.
// ---------------------------------------------------------------------------
struct PrepT { const void* src; int srcOff, K, N, dstOff; };
struct Prep { PrepT d[29]; int start[30]; };

__global__ void prep_k(Prep p, bf16* __restrict__ dst, const void* __restrict__ dtp) {
    const int mode = get_mode(dtp);
    int i = blockIdx.x * 256 + threadIdx.x;
    if (i >= p.start[29]) return;
    int s = 0;
    while (p.start[s + 1] <= i) ++s;
    int e = i - p.start[s];
    float v;
    if (p.d[s].N > 0) {
        int n = e / p.d[s].K, k = e % p.d[s].K;
        v = LD(p.d[s].src, (size_t)p.d[s].srcOff + (size_t)k * p.d[s].N + n, mode);
    } else {
        v = LD(p.d[s].src, (size_t)p.d[s].srcOff + e, mode);
    }
    dst[p.d[s].dstOff + e] = FB(v);
}

// Vectorized concat: X[32768][256] = bf16([xt | hx]).  Grid-stride.
__launch_bounds__(256)
__global__ void xcat_k(const void* __restrict__ xt, const void* __restrict__ hx,
                       u16* __restrict__ X) {
    const int mode = get_mode(xt);
    const int total = 32768 * 32;            // groups of 8 elements
    for (int gidx = blockIdx.x * 256 + threadIdx.x; gidx < total;
         gidx += gridDim.x * 256) {
        int r = gidx >> 5, gi = gidx & 31;
        const void* src = (gi < 16) ? xt : hx;
        int c = (gi & 15) << 3;
        u16 outv[8];
        if (mode) {
            const float* s = (const float*)src + (size_t)r * 128 + c;
            float4 a = *(const float4*)s;
            float4 b = *(const float4*)(s + 4);
            outv[0] = FBu(a.x); outv[1] = FBu(a.y); outv[2] = FBu(a.z); outv[3] = FBu(a.w);
            outv[4] = FBu(b.x); outv[5] = FBu(b.y); outv[6] = FBu(b.z); outv[7] = FBu(b.w);
        } else {
            *(uint4*)outv = *(const uint4*)((const u16*)src + (size_t)r * 128 + c);
        }
        *(uint4*)(X + (size_t)r * 256 + (gi << 3)) = *(const uint4*)outv;
    }
}

// ---------------------------------------------------------------------------
// MFMA GEMM, 64x128 tile (grid (1,512) -> 2 blocks/CU), BK=32, double-
// buffered LDS staging: stage(k+1) is issued BEFORE compute(k), one barrier
// per K-step (T3 minimum-2-phase). EPI 3: window-reverse/roll scatter-add
// into outf. 5: fp32 store.
// ---------------------------------------------------------------------------
template <int EPI>
__launch_bounds__(256)
__global__ void gemm_mfma(const u16* __restrict__ A, const u16* __restrict__ Bt,
                          const bf16* __restrict__ bias, bf16* __restrict__ outb,
                          float* __restrict__ outf, int M, int N, int K, int shift) {
    __shared__ __align__(16) u16 Als[2][2048];   // 64 rows x 32 k
    __shared__ __align__(16) u16 Bls[2][4096];   // 128 rows x 32 k
    const int tid = threadIdx.x;
    const int wave = tid >> 6, lane = tid & 63;
    const int q = lane >> 4, lr = lane & 15;
    const int wm = (wave >> 1) << 5, wn = (wave & 1) << 6;
    const int bm = blockIdx.y << 6, bn = blockIdx.x << 7;
    const f32x4 zero = {0.f, 0.f, 0.f, 0.f};
    f32x4 acc[2][4];
    #pragma unroll
    for (int i = 0; i < 2; ++i)
        #pragma unroll
        for (int j = 0; j < 4; ++j) acc[i][j] = zero;

    const int nk = K >> 5;
    {   // prologue: stage k-tile 0 into buffer 0
        int c = tid;
        async16(A + (size_t)(bm + (c >> 2)) * K + ((c & 3) << 3), Als[0] + (c << 3));
        #pragma unroll
        for (int c2 = tid; c2 < 512; c2 += 256)
            async16(Bt + (size_t)(bn + (c2 >> 2)) * K + ((c2 & 3) << 3), Bls[0] + (c2 << 3));
    }
    __syncthreads();

    for (int i = 0; i < nk; ++i) {
        const int cur = i & 1, nxt = cur ^ 1;
        if (i + 1 < nk) {                      // issue next-tile stage FIRST
            int k1 = (i + 1) << 5;
            int c = tid;
            async16(A + (size_t)(bm + (c >> 2)) * K + k1 + ((c & 3) << 3), Als[nxt] + (c << 3));
            #pragma unroll
            for (int c2 = tid; c2 < 512; c2 += 256)
                async16(Bt + (size_t)(bn + (c2 >> 2)) * K + k1 + ((c2 & 3) << 3), Bls[nxt] + (c2 << 3));
        }
        bf16x8 af[2], bfr[4];
        #pragma unroll
        for (int t = 0; t < 2; ++t)
            af[t] = *(const bf16x8*)(Als[cur] + ((wm + (t << 4) + lr) << 5) + (q << 3));
        #pragma unroll
        for (int t = 0; t < 4; ++t)
            bfr[t] = *(const bf16x8*)(Bls[cur] + ((wn + (t << 4) + lr) << 5) + (q << 3));
        #pragma unroll
        for (int mt = 0; mt < 2; ++mt)
            #pragma unroll
            for (int nt = 0; nt < 4; ++nt)
                acc[mt][nt] = __builtin_amdgcn_mfma_f32_16x16x32_bf16(
                    af[mt], bfr[nt], acc[mt][nt], 0, 0, 0);
        __syncthreads();                        // drains next-tile stage
    }

    #pragma unroll
    for (int nt = 0; nt < 4; ++nt) {
        int col = bn + wn + (nt << 4) + lr;
        float bv = BF(bias[col]);
        #pragma unroll
        for (int mt = 0; mt < 2; ++mt) {
            int row0 = bm + wm + (mt << 4) + (q << 2);
            #pragma unroll
            for (int i = 0; i < 4; ++i) {
                int r = row0 + i;
                float v = acc[mt][nt][i] + bv;
                size_t idx = (size_t)r * N + col;
                if (EPI == 0) {
                    outb[idx] = FB(v);
                } else if (EPI == 3) {
                    int b = r >> 12, rem = r & 4095;
                    int wi = rem >> 6, n = rem & 63;
                    int hp = ((wi >> 3) << 3) + (n >> 3);
                    int wp = ((wi & 7) << 3) + (n & 7);
                    int h = (hp + shift) & 63, w = (wp + shift) & 63;
                    outf[((size_t)((b << 12) + (h << 6) + w)) * 128 + col] += v;
                } else if (EPI == 5) {
                    outf[idx] = v;
                }
            }
        }
    }
}

// ---------------------------------------------------------------------------
// Fused LN1 (+roll+window gather) + QKV GEMM. Block = 64 windowed rows,
// 512 blocks. LDS: Ach 4x[64][36] padded | Bb double-buffered 2x16KB.
// Pipeline: 6 half-K sub-tiles (nc x khalf); stage(s+1) issued before
// compute(s); stage(0) issued before the LN so it hides under LN's loads.
// ---------------------------------------------------------------------------
__launch_bounds__(256)
__global__ void qkvln_k(const float* __restrict__ g, const u16* __restrict__ wtu,
                        const bf16* __restrict__ wtb, u16* __restrict__ qkv,
                        int d, int shift) {
    __shared__ __align__(16) u16 Ach[4 * CH_S];
    __shared__ __align__(16) u16 Bb[2][8192];
    const int tid = threadIdx.x;
    const int wave = tid >> 6, lane = tid & 63;
    const int q = lane >> 4, lr = lane & 15;
    const int wm = (wave >> 1) << 5, wn = (wave & 1) << 6;
    const int bm = blockIdx.x << 6;
    const u16* Wq = wtu + O_QKVW + d * 49152;

    // prologue stage: sub-tile 0 (nc=0, khalf=0) into Bb[0]
    #pragma unroll
    for (int i = tid; i < 1024; i += 256) {
        int kc = i >> 9, c = i & 511;
        async16(Wq + (size_t)(c >> 2) * 128 + (kc << 5) + ((c & 3) << 3),
                Bb[0] + (kc << 12) + (c << 3));
    }

    // LN1 with inverse-roll gather: thread = (row = tid>>2, qtr = tid&3)
    {
        int row = tid >> 2, qtr = tid & 3;
        int r = bm + row;
        int b = r >> 12, rem = r & 4095;
        int wi = rem >> 6, n = rem & 63;
        int hp = ((wi >> 3) << 3) + (n >> 3);
        int wp = ((wi & 7) << 3) + (n & 7);
        int h = (hp + shift) & 63, w = (wp + shift) & 63;
        int src = (b << 12) + (h << 6) + w;
        const float* gr = g + (size_t)src * 128 + qtr * 32;
        float vals[32];
        float s1 = 0.f, s2 = 0.f;
        #pragma unroll
        for (int i = 0; i < 8; ++i) {
            float4 v4 = *(const float4*)(gr + i * 4);
            vals[i * 4] = v4.x; vals[i * 4 + 1] = v4.y;
            vals[i * 4 + 2] = v4.z; vals[i * 4 + 3] = v4.w;
            s1 += v4.x + v4.y + v4.z + v4.w;
            s2 += v4.x * v4.x + v4.y * v4.y + v4.z * v4.z + v4.w * v4.w;
        }
        s1 += __shfl_xor(s1, 1); s1 += __shfl_xor(s1, 2);
        s2 += __shfl_xor(s2, 1); s2 += __shfl_xor(s2, 2);
        float mu = s1 * (1.f / 128.f);
        float var = s2 * (1.f / 128.f) - mu * mu;
        float inv = rsqrtf(var + 1e-5f);
        #pragma unroll
        for (int i = 0; i < 32; ++i) {
            int c = qtr * 32 + i;
            float o = (vals[i] - mu) * inv * BF(wtb[O_N1G + d * 128 + c])
                      + BF(wtb[O_N1B + d * 128 + c]);
            Ach[qtr * CH_S + row * ROW_S + i] = FBu(o);
        }
    }
    __syncthreads();   // drains stage(0); Ach visible

    const f32x4 zero = {0.f, 0.f, 0.f, 0.f};
    f32x4 acc[2][4];
    for (int s = 0; s < 6; ++s) {
        const int nc = s >> 1, kh = s & 1;
        const int bsel = s & 1;
        if (s < 5) {   // issue next sub-tile stage first
            int t = s + 1, nct = t >> 1, kht = t & 1;
            const u16* Bg = Wq + nct * 16384;
            #pragma unroll
            for (int i = tid; i < 1024; i += 256) {
                int kc = i >> 9, c = i & 511;
                async16(Bg + (size_t)(c >> 2) * 128 + (kht << 6) + (kc << 5) + ((c & 3) << 3),
                        Bb[t & 1] + (kc << 12) + (c << 3));
            }
        }
        if (kh == 0) {
            #pragma unroll
            for (int i = 0; i < 2; ++i)
                #pragma unroll
                for (int j = 0; j < 4; ++j) acc[i][j] = zero;
        }
        #pragma unroll
        for (int kc = 0; kc < 2; ++kc) {
            bf16x8 af[2], bfr[4];
            #pragma unroll
            for (int t = 0; t < 2; ++t)
                af[t] = *(const bf16x8*)(Ach + (2 * kh + kc) * CH_S + (wm + (t << 4) + lr) * ROW_S + (q << 3));
            #pragma unroll
            for (int t = 0; t < 4; ++t)
                bfr[t] = *(const bf16x8*)(Bb[bsel] + (kc << 12) + ((wn + (t << 4) + lr) << 5) + (q << 3));
            #pragma unroll
            for (int mt = 0; mt < 2; ++mt)
                #pragma unroll
                for (int nt = 0; nt < 4; ++nt)
                    acc[mt][nt] = __builtin_amdgcn_mfma_f32_16x16x32_bf16(
                        af[mt], bfr[nt], acc[mt][nt], 0, 0, 0);
        }
        if (kh == 1) {   // epilogue for this nc
            #pragma unroll
            for (int nt = 0; nt < 4; ++nt) {
                int col = wn + (nt << 4) + lr;
                float bv = BF(wtb[O_QKVB + d * 384 + nc * 128 + col]);
                #pragma unroll
                for (int mt = 0; mt < 2; ++mt) {
                    #pragma unroll
                    for (int i = 0; i < 4; ++i) {
                        int r = bm + wm + (mt << 4) + (q << 2) + i;
                        qkv[(size_t)r * 384 + nc * 128 + col] = FBu(acc[mt][nt][i] + bv);
                    }
                }
            }
        }
        if (s < 5) __syncthreads();   // drains stage(s+1); frees Bb[bsel]
    }
}

// ---------------------------------------------------------------------------
// Windowed MFMA attention: block = one window, wave = one head. Zero
// barriers (all LDS slices are wave-private). QK^T and PV on matrix cores;
// softmax in-register with 16-lane shfl_xor row reductions.
// ---------------------------------------------------------------------------
__launch_bounds__(256, 2)
__global__ void attn_k(const u16* __restrict__ qkv, const bf16* __restrict__ rp,
                       u16* __restrict__ outp, int shift) {
    __shared__ __align__(16) u16 vT[4][32][72];    // V^T per head (padded)
    __shared__ __align__(16) u16 pbuf[4][64][72];  // P bf16 per head (padded)
    const int wq = blockIdx.x;
    const int head = threadIdx.x >> 6;
    const int lane = threadIdx.x & 63;
    const int q8 = lane >> 4, lr = lane & 15;
    const size_t base = (size_t)wq * 64;
    const f32x4 zero = {0.f, 0.f, 0.f, 0.f};

    // stage V^T: thread=m-row, 4x bf16x8 global loads -> scattered u16 writes
    #pragma unroll
    for (int j = 0; j < 4; ++j) {
        bf16x8 vv = *(const bf16x8*)(qkv + (base + lane) * 384 + 256 + head * 32 + j * 8);
        #pragma unroll
        for (int e = 0; e < 8; ++e) vT[head][j * 8 + e][lane] = ((const u16*)&vv)[e];
    }

    // Q/K fragments direct from global (16B contiguous), S = Q K^T
    bf16x8 af[4], bfk[4];
    #pragma unroll
    for (int t = 0; t < 4; ++t) {
        af[t]  = *(const bf16x8*)(qkv + (base + t * 16 + lr) * 384 + head * 32 + q8 * 8);
        bfk[t] = *(const bf16x8*)(qkv + (base + t * 16 + lr) * 384 + 128 + head * 32 + q8 * 8);
    }
    f32x4 accs[4][4];
    #pragma unroll
    for (int rt = 0; rt < 4; ++rt)
        #pragma unroll
        for (int ct = 0; ct < 4; ++ct) accs[rt][ct] = zero;
    #pragma unroll
    for (int rt = 0; rt < 4; ++rt)
        #pragma unroll
        for (int ct = 0; ct < 4; ++ct)
            accs[rt][ct] = __builtin_amdgcn_mfma_f32_16x16x32_bf16(
                af[rt], bfk[ct], accs[rt][ct], 0, 0, 0);

    // scale + rel-pos bias + region mask + softmax + normalized bf16 P -> LDS
    const int wloc = wq & 63;
    const int wh = (wloc >> 3) << 3, wwb = (wloc & 7) << 3;
    #pragma unroll
    for (int rt = 0; rt < 4; ++rt) {
        #pragma unroll
        for (int i = 0; i < 4; ++i) {
            int r = rt * 16 + q8 * 4 + i;
            int ti = r >> 3, tj = r & 7;
            int regt = 0;
            if (shift) {
                int hp = wh + ti, wp = wwb + tj;
                int rh = hp < 56 ? 0 : (hp < 60 ? 1 : 2);
                int rw = wp < 56 ? 0 : (wp < 60 ? 1 : 2);
                regt = rh * 3 + rw;
            }
            float sv[4];
            float mx = -1e30f;
            #pragma unroll
            for (int ct = 0; ct < 4; ++ct) {
                int m = ct * 16 + lr;
                float a = accs[rt][ct][i] * 0.17677669529663687f;
                int idx = (ti - (m >> 3) + 7) * 15 + (tj - (m & 7) + 7);
                a += BF(rp[idx * 4 + head]);
                if (shift) {
                    int hp = wh + (m >> 3), wp = wwb + (m & 7);
                    int rh = hp < 56 ? 0 : (hp < 60 ? 1 : 2);
                    int rw = wp < 56 ? 0 : (wp < 60 ? 1 : 2);
                    if (regt != rh * 3 + rw) a -= 100.f;
                }
                sv[ct] = a;
                mx = fmaxf(mx, a);
            }
            mx = fmaxf(mx, __shfl_xor(mx, 1));
            mx = fmaxf(mx, __shfl_xor(mx, 2));
            mx = fmaxf(mx, __shfl_xor(mx, 4));
            mx = fmaxf(mx, __shfl_xor(mx, 8));
            float l = 0.f;
            #pragma unroll
            for (int ct = 0; ct < 4; ++ct) { sv[ct] = expf(sv[ct] - mx); l += sv[ct]; }
            l += __shfl_xor(l, 1); l += __shfl_xor(l, 2);
            l += __shfl_xor(l, 4); l += __shfl_xor(l, 8);
            float inv = 1.f / l;
            #pragma unroll
            for (int ct = 0; ct < 4; ++ct)
                pbuf[head][r][ct * 16 + lr] = FBu(sv[ct] * inv);
        }
    }

    // PV: O = P @ V  (A from pbuf, B from vT)
    f32x4 acco[4][2];
    #pragma unroll
    for (int rt = 0; rt < 4; ++rt) { acco[rt][0] = zero; acco[rt][1] = zero; }
    #pragma unroll
    for (int mh = 0; mh < 2; ++mh) {
        bf16x8 vb[2];
        #pragma unroll
        for (int dt = 0; dt < 2; ++dt)
            vb[dt] = *(const bf16x8*)(&vT[head][dt * 16 + lr][mh * 32 + q8 * 8]);
        #pragma unroll
        for (int rt = 0; rt < 4; ++rt) {
            bf16x8 pa = *(const bf16x8*)(&pbuf[head][rt * 16 + lr][mh * 32 + q8 * 8]);
            #pragma unroll
            for (int dt = 0; dt < 2; ++dt)
                acco[rt][dt] = __builtin_amdgcn_mfma_f32_16x16x32_bf16(
                    pa, vb[dt], acco[rt][dt], 0, 0, 0);
        }
    }

    // store O rows (already normalized)
    #pragma unroll
    for (int rt = 0; rt < 4; ++rt)
        #pragma unroll
        for (int dt = 0; dt < 2; ++dt)
            #pragma unroll
            for (int i = 0; i < 4; ++i) {
                int r = rt * 16 + q8 * 4 + i;
                outp[(base + r) * 128 + head * 32 + dt * 16 + lr] = FBu(acco[rt][dt][i]);
            }
}

// ---------------------------------------------------------------------------
// Fused MLP: LN2 + f1 + GELU + f2 + residual into g (+ bf16 copy to gbf).
// Block = 64 rows, 512 blocks. LDS: Ach | bufB1 16KB | bufB2 16KB | buf2.
// Pipeline: stage B1(0) before LN; per h: issue B2(h), compute MFMA1+GELU,
// barrier, issue B1(h+1), compute MFMA2, barrier. 2 barriers/h,
// stage latency hidden under compute.
// ---------------------------------------------------------------------------
__launch_bounds__(256)
__global__ void mlp_k(float* __restrict__ g, bf16* __restrict__ gbf,
                      const u16* __restrict__ wtu, const bf16* __restrict__ wtb,
                      int d) {
    __shared__ __align__(16) u16 Ach[4 * CH_S];
    __shared__ __align__(16) u16 bufB1[8192];
    __shared__ __align__(16) u16 bufB2[8192];
    __shared__ __align__(16) u16 buf2[2 * CH_S];
    const int tid = threadIdx.x;
    const int wave = tid >> 6, lane = tid & 63;
    const int q = lane >> 4, lr = lane & 15;
    const int wm = (wave >> 1) << 5;   // 0 / 32 (row split)
    const int wn0 = (wave & 1) << 5;   // stage1: 32-hcol split
    const int wn = (wave & 1) << 6;    // stage2: 64-ncol split
    const int bm = blockIdx.x << 6;

    // prologue stage: B1 chunk h=0 (hides under LN's global loads)
    {
        const u16* B1g = wtu + O_F1W + d * 65536;
        #pragma unroll
        for (int i = tid; i < 1024; i += 256) {
            int kc = i >> 8, c = i & 255;
            async16(B1g + (c >> 2) * 128 + (kc << 5) + ((c & 3) << 3),
                    bufB1 + (kc << 11) + (c << 3));
        }
    }

    // LN2: thread = (row = tid>>2, qtr = tid&3)
    {
        int row = tid >> 2, qtr = tid & 3;
        const float* gr = g + (size_t)(bm + row) * 128 + qtr * 32;
        float vals[32];
        float s1 = 0.f, s2 = 0.f;
        #pragma unroll
        for (int i = 0; i < 8; ++i) {
            float4 v4 = *(const float4*)(gr + i * 4);
            vals[i * 4] = v4.x; vals[i * 4 + 1] = v4.y;
            vals[i * 4 + 2] = v4.z; vals[i * 4 + 3] = v4.w;
            s1 += v4.x + v4.y + v4.z + v4.w;
            s2 += v4.x * v4.x + v4.y * v4.y + v4.z * v4.z + v4.w * v4.w;
        }
        s1 += __shfl_xor(s1, 1); s1 += __shfl_xor(s1, 2);
        s2 += __shfl_xor(s2, 1); s2 += __shfl_xor(s2, 2);
        float mu = s1 * (1.f / 128.f);
        float var = s2 * (1.f / 128.f) - mu * mu;
        float inv = rsqrtf(var + 1e-5f);
        #pragma unroll
        for (int i = 0; i < 32; ++i) {
            int c = qtr * 32 + i;
            float o = (vals[i] - mu) * inv * BF(wtb[O_N2G + d * 128 + c])
                      + BF(wtb[O_N2B + d * 128 + c]);
            Ach[qtr * CH_S + row * ROW_S + i] = FBu(o);
        }
    }
    __syncthreads();   // drains B1(0); Ach visible

    const f32x4 zero = {0.f, 0.f, 0.f, 0.f};
    f32x4 acc2[2][4];
    #pragma unroll
    for (int i = 0; i < 2; ++i)
        #pragma unroll
        for (int j = 0; j < 4; ++j) acc2[i][j] = zero;

    for (int h = 0; h < 8; ++h) {
        // issue B2(h) stage first (hides under MFMA1 + GELU)
        {
            const u16* B2g = wtu + O_F2W + d * 65536 + h * 64;
            #pragma unroll
            for (int i = tid; i < 1024; i += 256) {
                int kc = i >> 9, c = i & 511;
                async16(B2g + (size_t)(c >> 2) * 512 + (kc << 5) + ((c & 3) << 3),
                        bufB2 + (kc << 12) + (c << 3));
            }
        }
        // MFMA1 from Ach x bufB1 (B1(h), ready from previous barrier)
        f32x4 acc1[2][2];
        #pragma unroll
        for (int i = 0; i < 2; ++i) { acc1[i][0] = zero; acc1[i][1] = zero; }
        #pragma unroll
        for (int k0 = 0; k0 < 4; ++k0) {
            bf16x8 af[2], bfr[2];
            #pragma unroll
            for (int t = 0; t < 2; ++t) {
                af[t]  = *(const bf16x8*)(Ach + k0 * CH_S + (wm + (t << 4) + lr) * ROW_S + (q << 3));
                bfr[t] = *(const bf16x8*)(bufB1 + (k0 << 11) + ((wn0 + (t << 4) + lr) << 5) + (q << 3));
            }
            #pragma unroll
            for (int mt = 0; mt < 2; ++mt)
                #pragma unroll
                for (int nt = 0; nt < 2; ++nt)
                    acc1[mt][nt] = __builtin_amdgcn_mfma_f32_16x16x32_bf16(
                        af[mt], bfr[nt], acc1[mt][nt], 0, 0, 0);
        }
        // GELU -> hidden chunks (padded) in buf2
        #pragma unroll
        for (int nt = 0; nt < 2; ++nt) {
            int c = wn0 + (nt << 4) + lr;
            float hb = BF(wtb[O_F1B + d * 512 + h * 64 + c]);
            #pragma unroll
            for (int mt = 0; mt < 2; ++mt) {
                #pragma unroll
                for (int i = 0; i < 4; ++i) {
                    int r = wm + (mt << 4) + (q << 2) + i;
                    float v = acc1[mt][nt][i] + hb;
                    float ge = 0.5f * v * (1.0f + erff(v * 0.70710678118654752f));
                    buf2[(c >> 5) * CH_S + r * ROW_S + (c & 31)] = FBu(ge);
                }
            }
        }
        __syncthreads();   // drains B2(h); buf2 visible; bufB1 free
        // issue B1(h+1) stage (hides under MFMA2)
        if (h < 7) {
            const u16* B1g = wtu + O_F1W + d * 65536 + (h + 1) * 8192;
            #pragma unroll
            for (int i = tid; i < 1024; i += 256) {
                int kc = i >> 8, c = i & 255;
                async16(B1g + (c >> 2) * 128 + (kc << 5) + ((c & 3) << 3),
                        bufB1 + (kc << 11) + (c << 3));
            }
        }
        // MFMA2 from buf2 x bufB2
        #pragma unroll
        for (int kc = 0; kc < 2; ++kc) {
            bf16x8 ah[2], b2[4];
            #pragma unroll
            for (int t = 0; t < 2; ++t)
                ah[t] = *(const bf16x8*)(buf2 + kc * CH_S + (wm + (t << 4) + lr) * ROW_S + (q << 3));
            #pragma unroll
            for (int t = 0; t < 4; ++t)
                b2[t] = *(const bf16x8*)(bufB2 + (kc << 12) + ((wn + (t << 4) + lr) << 5) + (q << 3));
            #pragma unroll
            for (int mt = 0; mt < 2; ++mt)
                #pragma unroll
                for (int nt = 0; nt < 4; ++nt)
                    acc2[mt][nt] = __builtin_amdgcn_mfma_f32_16x16x32_bf16(
                        ah[mt], b2[nt], acc2[mt][nt], 0, 0, 0);
        }
        __syncthreads();   // drains B1(h+1); bufB2/buf2 free
    }
    #pragma unroll
    for (int nt = 0; nt < 4; ++nt) {
        int col = wn + (nt << 4) + lr;
        float bv = BF(wtb[O_F2B + d * 128 + col]);
        #pragma unroll
        for (int mt = 0; mt < 2; ++mt) {
            #pragma unroll
            for (int i = 0; i < 4; ++i) {
                int r = bm + wm + (mt << 4) + (q << 2) + i;
                size_t idx = (size_t)r * 128 + col;
                float nv = g[idx] + acc2[mt][nt][i] + bv;
                g[idx] = nv;
                gbf[idx] = FB(nv);
            }
        }
    }
}

// ---------------------------------------------------------------------------
// Fused fusion chain + LSTM gate -> out. 32-row tiles, 1024 blocks
// (4 blocks/CU -> 2x the waves of the 64-row version, hides the direct
// global-load latency the counters showed). Each wave: 32 rows x 32 cols.
// GEMM operands direct from global; ReLU intermediate in padded LDS
// (4 chunks of [32][36], +16 skew). 1 barrier total.
// ---------------------------------------------------------------------------
__launch_bounds__(256, 4)
__global__ void fuse3_k(const u16* __restrict__ Aloc, const u16* __restrict__ Ag,
                        const u16* __restrict__ wtu, const bf16* __restrict__ wtb,
                        const void* __restrict__ cx, void* __restrict__ out,
                        const void* __restrict__ dtp) {
    __shared__ __align__(16) u16 relb[4 * CH32_S];
    const int mode = get_mode(dtp);
    const int tid = threadIdx.x;
    const int wave = tid >> 6, lane = tid & 63;
    const int q = lane >> 4, lr = lane & 15;
    const int wn = wave << 5;          // 4 waves x 32-col split
    const int bm = blockIdx.x << 5;    // 32-row tile
    const f32x4 zero = {0.f, 0.f, 0.f, 0.f};
    f32x4 acc1[2][2], acc2[2][2];
    #pragma unroll
    for (int i = 0; i < 2; ++i)
        #pragma unroll
        for (int j = 0; j < 2; ++j) { acc1[i][j] = zero; acc2[i][j] = zero; }

    #pragma unroll
    for (int k0 = 0; k0 < 4; ++k0) {
        bf16x8 al[2], ag[2], blf[2], bgf[2];
        #pragma unroll
        for (int t = 0; t < 2; ++t) {
            size_t off = (size_t)(bm + (t << 4) + lr) * 128 + (k0 << 5) + (q << 3);
            al[t] = *(const bf16x8*)(Aloc + off);
            ag[t] = *(const bf16x8*)(Ag + off);
        }
        #pragma unroll
        for (int t = 0; t < 2; ++t) {
            int woff = ((wn + (t << 4) + lr) << 7) + (k0 << 5) + (q << 3);
            blf[t] = *(const bf16x8*)(wtu + O_LFW + woff);
            bgf[t] = *(const bf16x8*)(wtu + O_GFW + woff);
        }
        #pragma unroll
        for (int mt = 0; mt < 2; ++mt)
            #pragma unroll
            for (int nt = 0; nt < 2; ++nt) {
                acc1[mt][nt] = __builtin_amdgcn_mfma_f32_16x16x32_bf16(
                    al[mt], blf[nt], acc1[mt][nt], 0, 0, 0);
                acc2[mt][nt] = __builtin_amdgcn_mfma_f32_16x16x32_bf16(
                    ag[mt], bgf[nt], acc2[mt][nt], 0, 0, 0);
            }
    }
    // relu((local@lf + lfb) * (g@gf + gfb)) -> padded LDS (chunk = wave)
    #pragma unroll
    for (int nt = 0; nt < 2; ++nt) {
        int c = wn + (nt << 4) + lr;
        float lfb = BF(wtb[O_LFB + c]);
        float gfb = BF(wtb[O_GFB + c]);
        #pragma unroll
        for (int mt = 0; mt < 2; ++mt) {
            #pragma unroll
            for (int i = 0; i < 4; ++i) {
                int r = (mt << 4) + (q << 2) + i;
                float t1 = acc1[mt][nt][i] + lfb;
                float t2 = acc2[mt][nt][i] + gfb;
                float rel = t1 * t2;
                relb[(c >> 5) * CH32_S + r * ROW_S + (c & 31)] = FBu(rel > 0.f ? rel : 0.f);
            }
        }
    }
    __syncthreads();
    f32x4 acc3[2][2];
    #pragma unroll
    for (int i = 0; i < 2; ++i)
        #pragma unroll
        for (int j = 0; j < 2; ++j) acc3[i][j] = zero;
    #pragma unroll
    for (int k0 = 0; k0 < 4; ++k0) {
        bf16x8 ar[2], bff[2];
        #pragma unroll
        for (int t = 0; t < 2; ++t)
            ar[t] = *(const bf16x8*)(relb + k0 * CH32_S + ((t << 4) + lr) * ROW_S + (q << 3));
        #pragma unroll
        for (int t = 0; t < 2; ++t)
            bff[t] = *(const bf16x8*)(wtu + O_FFW + ((wn + (t << 4) + lr) << 7) + (k0 << 5) + (q << 3));
        #pragma unroll
        for (int mt = 0; mt < 2; ++mt)
            #pragma unroll
            for (int nt = 0; nt < 2; ++nt)
                acc3[mt][nt] = __builtin_amdgcn_mfma_f32_16x16x32_bf16(
                    ar[mt], bff[nt], acc3[mt][nt], 0, 0, 0);
    }
    // LSTM gating epilogue
    #pragma unroll
    for (int nt = 0; nt < 2; ++nt) {
        int col = wn + (nt << 4) + lr;
        float ffb = BF(wtb[O_FFB + col]);
        #pragma unroll
        for (int mt = 0; mt < 2; ++mt) {
            #pragma unroll
            for (int i = 0; i < 4; ++i) {
                int r = bm + (mt << 4) + (q << 2) + i;
                size_t idx = (size_t)r * 128 + col;
                float v = acc3[mt][nt][i] + ffb;
                float gate = 1.f / (1.f + expf(-v));
                float cell = tanhf(v);
                float cy = gate * (LD(cx, idx, mode) + cell);
                float hy = gate * tanhf(cy);
                if (mode) ((float*)out)[idx] = hy;
                else      ((bf16*)out)[idx] = FB(hy);
            }
        }
    }
}

// ---------------------------------------------------------------------------
// Deformable conv1d, stage 1: offset/mask conv. One WAVE per output position.
// ---------------------------------------------------------------------------
__launch_bounds__(256)
__global__ void offmask_k(const void* __restrict__ xt, const bf16* __restrict__ wtb,
                          float4* __restrict__ om) {
    const int mode = get_mode(xt);
    const int wave = threadIdx.x >> 6, lane = threadIdx.x & 63;
    const int gl = blockIdx.x * 4 + wave;
    const int b = gl >> 12, l = gl & 4095;
    float wo[3][3][2], wmk[3][3][2];
    #pragma unroll
    for (int k = 0; k < 3; ++k)
        #pragma unroll
        for (int j = 0; j < 3; ++j) {
            wo[k][j][0]  = BF(wtb[O_OW + (k * 128 + lane) * 3 + j]);
            wo[k][j][1]  = BF(wtb[O_OW + (k * 128 + lane + 64) * 3 + j]);
            wmk[k][j][0] = BF(wtb[O_MW + (k * 128 + lane) * 3 + j]);
            wmk[k][j][1] = BF(wtb[O_MW + (k * 128 + lane + 64) * 3 + j]);
        }
    float a6[6] = {};
    #pragma unroll
    for (int j = 0; j < 3; ++j) {
        int row = l + j - 1;
        if (row >= 0 && row < 4096) {
            size_t base = ((size_t)(b << 12) + row) * 128;
            float x0 = LD(xt, base + lane, mode);
            float x1 = LD(xt, base + lane + 64, mode);
            #pragma unroll
            for (int k = 0; k < 3; ++k) {
                a6[k]     += x0 * wo[k][j][0]  + x1 * wo[k][j][1];
                a6[3 + k] += x0 * wmk[k][j][0] + x1 * wmk[k][j][1];
            }
        }
    }
    #pragma unroll
    for (int off = 32; off > 0; off >>= 1)
        #pragma unroll
        for (int k = 0; k < 6; ++k) a6[k] += __shfl_down(a6[k], off);
    if (lane == 0) {
        #pragma unroll
        for (int k = 0; k < 3; ++k) {
            float off = a6[k] + BF(wtb[O_OB + k]);
            float pos = fminf(fmaxf((float)l + off, 0.f), 4095.f);
            float fpf = floorf(pos);
            float mv = a6[3 + k] + BF(wtb[O_MB + k]);
            float mk = 1.f / (1.f + expf(-mv));
            om[(size_t)gl * 3 + k] = make_float4(fpf, pos - fpf, mk, 0.f);
        }
    }
}

// ---------------------------------------------------------------------------
// Deformable conv1d, stage 2: sampling + transpose to (B,C,L) bf16.
// ---------------------------------------------------------------------------
__launch_bounds__(512)
__global__ void sample_k(const void* __restrict__ xt, const float4* __restrict__ om,
                         bf16* __restrict__ outL) {
    __shared__ __align__(16) u16 ot[128 * 72];
    const int mode = get_mode(xt);
    const int tid = threadIdx.x;
    const int b = blockIdx.x >> 6;
    const int l0 = (blockIdx.x & 63) << 6;
    const int c = tid & 127, lh = tid >> 7;
    for (int it = 0; it < 16; ++it) {
        int l_loc = lh * 16 + it;
        size_t gl = (size_t)(b << 12) + l0 + l_loc;
        float o = 0.f;
        #pragma unroll
        for (int k = 0; k < 3; ++k) {
            float4 v = om[gl * 3 + k];
            int fp = (int)v.x;
            int cp = fp + 1 > 4095 ? 4095 : fp + 1;
            float al = v.y, mk = v.z;
            float xf = LD(xt, ((size_t)(b << 12) + fp) * 128 + c, mode);
            float xc = LD(xt, ((size_t)(b << 12) + cp) * 128 + c, mode);
            o += (xf * (1.f - al) + xc * al) * mk;
        }
        ot[c * 72 + l_loc] = FBu(o);
    }
    __syncthreads();
    #pragma unroll
    for (int pass = 0; pass < 2; ++pass) {
        int cc = pass * 64 + (tid >> 3);
        int oo = tid & 7;
        const uint4 v = *(const uint4*)(ot + cc * 72 + oo * 8);
        *(uint4*)(outL + (size_t)b * 524288 + (size_t)cc * 4096 + l0 + oo * 8) = v;
    }
}

extern "C" void kernel_launch(void* const* d_in, const int* in_sizes, int n_in,
                              void* d_out, int out_size, void* d_ws, size_t ws_size,
                              hipStream_t stream) {
    (void)out_size; (void)ws_size;
    int I[28] = {0,1,2,3,4,5,6,7,8,9,10,11,12,13,14,15,16,17,18,19,20,21,22,23,24,25,26,27};
    if (n_in >= 28 && in_sizes[7] != 98304 && in_sizes[23] == 98304 && in_sizes[26] == 1800) {
        int alt[28] = {27, 9, 0, 25, 24, 15, 14, 23, 22, 26, 21, 20, 17, 16,
                       2, 1, 4, 3, 19, 18, 13, 12, 11, 10, 8, 7, 6, 5};
        for (int i = 0; i < 28; ++i) I[i] = alt[i];
    }
    const void* xt = d_in[I[0]];
    const void* hx = d_in[I[1]];
    const void* cx = d_in[I[2]];

    char* wsb = (char*)d_ws;
    float* g    = (float*)wsb;                    // fp32 residual [0,16M)
    u16*   Abf  = (u16*)(wsb + 16777216);         // bf16(g)
    u16*   Bbf  = (u16*)(wsb + 25165824);         // Xcat / qkv
    u16*   Cbf  = (u16*)(wsb + 50331648);         // attn-out / local
    bf16*  wtb  = (bf16*)(wsb + 58720256);
    u16*   wtu  = (u16*)wtb;
    float4* om  = (float4*)(wsb + 25165824);      // reuses Bbf after last attn

    Prep p;
    PrepT descs[29] = {
        {d_in[I[3]],  0,     256, 128, O_REDW},
        {d_in[I[7]],  0,     128, 384, O_QKVW},
        {d_in[I[7]],  49152, 128, 384, O_QKVW + 49152},
        {d_in[I[10]], 0,     128, 128, O_PW},
        {d_in[I[10]], 16384, 128, 128, O_PW + 16384},
        {d_in[I[14]], 0,     128, 512, O_F1W},
        {d_in[I[14]], 65536, 128, 512, O_F1W + 65536},
        {d_in[I[16]], 0,     512, 128, O_F2W},
        {d_in[I[16]], 65536, 512, 128, O_F2W + 65536},
        {d_in[I[22]], 0,     128, 128, O_LFW},
        {d_in[I[24]], 0,     128, 128, O_GFW},
        {d_in[I[26]], 0,     128, 128, O_FFW},
        {d_in[I[4]],  0,  128, 0, O_REDB},
        {d_in[I[8]],  0,  768, 0, O_QKVB},
        {d_in[I[11]], 0,  256, 0, O_PB},
        {d_in[I[15]], 0, 1024, 0, O_F1B},
        {d_in[I[17]], 0,  256, 0, O_F2B},
        {d_in[I[23]], 0,  128, 0, O_LFB},
        {d_in[I[25]], 0,  128, 0, O_GFB},
        {d_in[I[27]], 0,  128, 0, O_FFB},
        {d_in[I[9]],  0, 1800, 0, O_RP},
        {d_in[I[5]],  0,  256, 0, O_N1G},
        {d_in[I[6]],  0,  256, 0, O_N1B},
        {d_in[I[12]], 0,  256, 0, O_N2G},
        {d_in[I[13]], 0,  256, 0, O_N2B},
        {d_in[I[18]], 0, 1152, 0, O_OW},
        {d_in[I[19]], 0,    3, 0, O_OB},
        {d_in[I[20]], 0, 1152, 0, O_MW},
        {d_in[I[21]], 0,    3, 0, O_MB},
    };
    int cum = 0;
    for (int i = 0; i < 29; ++i) {
        p.d[i] = descs[i];
        p.start[i] = cum;
        cum += (descs[i].N > 0) ? descs[i].K * descs[i].N : descs[i].K;
    }
    p.start[29] = cum;

    prep_k<<<(cum + 255) / 256, 256, 0, stream>>>(p, wtb, xt);
    xcat_k<<<1024, 256, 0, stream>>>(xt, hx, Bbf);

    // g = Xcat @ red_w + red_b (fp32)
    gemm_mfma<5><<<dim3(1, 512), 256, 0, stream>>>(Bbf, wtu + O_REDW, wtb + O_REDB,
                                                   nullptr, g, 32768, 128, 256, 0);

    for (int d = 0; d < 2; ++d) {
        int shift = d ? 4 : 0;
        qkvln_k<<<512, 256, 0, stream>>>(g, wtu, wtb, Bbf, d, shift);
        attn_k<<<512, 256, 0, stream>>>(Bbf, wtb + O_RP + d * 900, Cbf, shift);
        gemm_mfma<3><<<dim3(1, 512), 256, 0, stream>>>(Cbf, wtu + O_PW + d * 16384,
                                                       wtb + O_PB + d * 128, nullptr, g,
                                                       32768, 128, 128, shift);
        mlp_k<<<512, 256, 0, stream>>>(g, (bf16*)Abf, wtu, wtb, d);
    }

    // local branch: offset/mask conv (wave-per-l), then sampling -> Cbf (B,C,L)
    offmask_k<<<8192, 256, 0, stream>>>(xt, wtb, om);
    sample_k<<<512, 512, 0, stream>>>(xt, om, (bf16*)Cbf);
    // fused fusion chain + LSTM -> out
    fuse3_k<<<1024, 256, 0, stream>>>(Cbf, Abf, wtu, wtb, cx, d_out, xt);
}

// Round 6
// 401.668 us; speedup vs baseline: 1.3462x; 1.0081x over previous
//
#include <hip/hip_runtime.h>
#include <hip/hip_bf16.h>
#include <math.h>

typedef __hip_bfloat16 bf16;
typedef unsigned short u16;
#define BF(x) __bfloat162float(x)
static __device__ __forceinline__ bf16 FB(float x) { return __float2bfloat16(x); }
static __device__ __forceinline__ u16 FBu(float x) {
    bf16 b = __float2bfloat16(x);
    return *(u16*)&b;
}

typedef __attribute__((ext_vector_type(4))) float f32x4;
typedef __attribute__((ext_vector_type(8))) __bf16 bf16x8;

// Problem: B=8, H=W=64, C=128, L=4096, NH=4, HD=32, WIN=8, N=64, NW=64, M=32768.

// Wt (prepped bf16 weights) element offsets
#define O_REDW 0
#define O_QKVW 32768
#define O_PW   131072
#define O_F1W  163840
#define O_F2W  294912
#define O_LFW  425984
#define O_GFW  442368
#define O_FFW  458752
#define O_REDB 475136
#define O_QKVB 475264
#define O_PB   476032
#define O_F1B  476288
#define O_F2B  477312
#define O_LFB  477568
#define O_GFB  477696
#define O_FFB  477824
#define O_RP   477952
#define O_N1G  479752
#define O_N1B  480008
#define O_N2G  480264
#define O_N2B  480520
#define O_OW   480776
#define O_OB   481928
#define O_MW   481931
#define O_MB   483083

// Padded LDS tile geometry for VALU-written A-tiles (kills 16-way conflicts):
// row stride 36 u16 (72 B = 18 banks), chunk stride 2320 u16 (64-row chunks).
#define ROW_S 36
#define CH_S  2320
// 32-row chunk variant (fuse3): 32*36 + 16 skew
#define CH32_S 1168

// Runtime input-dtype detection from xt (N(0,1) data). 0 = bf16, 1 = fp32.
__device__ __forceinline__ int get_mode(const void* xt) {
    const unsigned* w = (const unsigned*)xt;
    int zlo = 0, inband = 0;
    #pragma unroll
    for (int i = 0; i < 32; ++i) {
        unsigned lo = w[i] & 0xFFFFu;
        int e = (int)((lo >> 7) & 0xFF);
        zlo += (lo == 0u || lo == 0x8000u);
        inband += (e >= 100 && e <= 140);
    }
    if (zlo >= 29) return 1;
    return (inband >= 20) ? 0 : 1;
}

__device__ __forceinline__ float LD(const void* p, size_t i, int mode) {
    return mode ? ((const float*)p)[i] : BF(((const bf16*)p)[i]);
}

// async global->LDS, 16 bytes per lane
__device__ __forceinline__ void async16(const u16* g, u16* l) {
    __builtin_amdgcn_global_load_lds(
        (const __attribute__((address_space(1))) unsigned int*)g,
        (__attribute__((address_space(3))) unsigned int*)l, 16, 0, 0);
}

// ---------------------------------------------------------------------------
// Prep: transpose weights to [N][K] bf16 + convert params.
// ---------------------------------------------------------------------------
struct PrepT { const void* src; int srcOff, K, N, dstOff; };
struct Prep { PrepT d[29]; int start[30]; };

__global__ void prep_k(Prep p, bf16* __restrict__ dst, const void* __restrict__ dtp) {
    const int mode = get_mode(dtp);
    int i = blockIdx.x * 256 + threadIdx.x;
    if (i >= p.start[29]) return;
    int s = 0;
    while (p.start[s + 1] <= i) ++s;
    int e = i - p.start[s];
    float v;
    if (p.d[s].N > 0) {
        int n = e / p.d[s].K, k = e % p.d[s].K;
        v = LD(p.d[s].src, (size_t)p.d[s].srcOff + (size_t)k * p.d[s].N + n, mode);
    } else {
        v = LD(p.d[s].src, (size_t)p.d[s].srcOff + e, mode);
    }
    dst[p.d[s].dstOff + e] = FB(v);
}

// Vectorized concat: X[32768][256] = bf16([xt | hx]).  Grid-stride.
__launch_bounds__(256)
__global__ void xcat_k(const void* __restrict__ xt, const void* __restrict__ hx,
                       u16* __restrict__ X) {
    const int mode = get_mode(xt);
    const int total = 32768 * 32;            // groups of 8 elements
    for (int gidx = blockIdx.x * 256 + threadIdx.x; gidx < total;
         gidx += gridDim.x * 256) {
        int r = gidx >> 5, gi = gidx & 31;
        const void* src = (gi < 16) ? xt : hx;
        int c = (gi & 15) << 3;
        u16 outv[8];
        if (mode) {
            const float* s = (const float*)src + (size_t)r * 128 + c;
            float4 a = *(const float4*)s;
            float4 b = *(const float4*)(s + 4);
            outv[0] = FBu(a.x); outv[1] = FBu(a.y); outv[2] = FBu(a.z); outv[3] = FBu(a.w);
            outv[4] = FBu(b.x); outv[5] = FBu(b.y); outv[6] = FBu(b.z); outv[7] = FBu(b.w);
        } else {
            *(uint4*)outv = *(const uint4*)((const u16*)src + (size_t)r * 128 + c);
        }
        *(uint4*)(X + (size_t)r * 256 + (gi << 3)) = *(const uint4*)outv;
    }
}

// ---------------------------------------------------------------------------
// MFMA GEMM, 64x128 tile (grid (1,512) -> 2 blocks/CU), BK=32, double-
// buffered LDS staging: stage(k+1) is issued BEFORE compute(k), one barrier
// per K-step (T3 minimum-2-phase). EPI 5: fp32 store.
// ---------------------------------------------------------------------------
template <int EPI>
__launch_bounds__(256)
__global__ void gemm_mfma(const u16* __restrict__ A, const u16* __restrict__ Bt,
                          const bf16* __restrict__ bias, bf16* __restrict__ outb,
                          float* __restrict__ outf, int M, int N, int K, int shift) {
    __shared__ __align__(16) u16 Als[2][2048];   // 64 rows x 32 k
    __shared__ __align__(16) u16 Bls[2][4096];   // 128 rows x 32 k
    const int tid = threadIdx.x;
    const int wave = tid >> 6, lane = tid & 63;
    const int q = lane >> 4, lr = lane & 15;
    const int wm = (wave >> 1) << 5, wn = (wave & 1) << 6;
    const int bm = blockIdx.y << 6, bn = blockIdx.x << 7;
    const f32x4 zero = {0.f, 0.f, 0.f, 0.f};
    f32x4 acc[2][4];
    #pragma unroll
    for (int i = 0; i < 2; ++i)
        #pragma unroll
        for (int j = 0; j < 4; ++j) acc[i][j] = zero;

    const int nk = K >> 5;
    {   // prologue: stage k-tile 0 into buffer 0
        int c = tid;
        async16(A + (size_t)(bm + (c >> 2)) * K + ((c & 3) << 3), Als[0] + (c << 3));
        #pragma unroll
        for (int c2 = tid; c2 < 512; c2 += 256)
            async16(Bt + (size_t)(bn + (c2 >> 2)) * K + ((c2 & 3) << 3), Bls[0] + (c2 << 3));
    }
    __syncthreads();

    for (int i = 0; i < nk; ++i) {
        const int cur = i & 1, nxt = cur ^ 1;
        if (i + 1 < nk) {                      // issue next-tile stage FIRST
            int k1 = (i + 1) << 5;
            int c = tid;
            async16(A + (size_t)(bm + (c >> 2)) * K + k1 + ((c & 3) << 3), Als[nxt] + (c << 3));
            #pragma unroll
            for (int c2 = tid; c2 < 512; c2 += 256)
                async16(Bt + (size_t)(bn + (c2 >> 2)) * K + k1 + ((c2 & 3) << 3), Bls[nxt] + (c2 << 3));
        }
        bf16x8 af[2], bfr[4];
        #pragma unroll
        for (int t = 0; t < 2; ++t)
            af[t] = *(const bf16x8*)(Als[cur] + ((wm + (t << 4) + lr) << 5) + (q << 3));
        #pragma unroll
        for (int t = 0; t < 4; ++t)
            bfr[t] = *(const bf16x8*)(Bls[cur] + ((wn + (t << 4) + lr) << 5) + (q << 3));
        #pragma unroll
        for (int mt = 0; mt < 2; ++mt)
            #pragma unroll
            for (int nt = 0; nt < 4; ++nt)
                acc[mt][nt] = __builtin_amdgcn_mfma_f32_16x16x32_bf16(
                    af[mt], bfr[nt], acc[mt][nt], 0, 0, 0);
        __syncthreads();                        // drains next-tile stage
    }

    #pragma unroll
    for (int nt = 0; nt < 4; ++nt) {
        int col = bn + wn + (nt << 4) + lr;
        float bv = BF(bias[col]);
        #pragma unroll
        for (int mt = 0; mt < 2; ++mt) {
            int row0 = bm + wm + (mt << 4) + (q << 2);
            #pragma unroll
            for (int i = 0; i < 4; ++i) {
                int r = row0 + i;
                float v = acc[mt][nt][i] + bv;
                size_t idx = (size_t)r * N + col;
                if (EPI == 0) {
                    outb[idx] = FB(v);
                } else if (EPI == 5) {
                    outf[idx] = v;
                }
            }
        }
    }
}

// ---------------------------------------------------------------------------
// Fused LN1 (+roll+window gather) + QKV GEMM. Block = 64 windowed rows,
// 512 blocks. LDS: Ach 4x[64][36] padded | Bb double-buffered 2x16KB.
// Pipeline: 6 half-K sub-tiles (nc x khalf); stage(s+1) issued before
// compute(s); stage(0) issued before the LN so it hides under LN's loads.
// ---------------------------------------------------------------------------
__launch_bounds__(256)
__global__ void qkvln_k(const float* __restrict__ g, const u16* __restrict__ wtu,
                        const bf16* __restrict__ wtb, u16* __restrict__ qkv,
                        int d, int shift) {
    __shared__ __align__(16) u16 Ach[4 * CH_S];
    __shared__ __align__(16) u16 Bb[2][8192];
    const int tid = threadIdx.x;
    const int wave = tid >> 6, lane = tid & 63;
    const int q = lane >> 4, lr = lane & 15;
    const int wm = (wave >> 1) << 5, wn = (wave & 1) << 6;
    const int bm = blockIdx.x << 6;
    const u16* Wq = wtu + O_QKVW + d * 49152;

    // prologue stage: sub-tile 0 (nc=0, khalf=0) into Bb[0]
    #pragma unroll
    for (int i = tid; i < 1024; i += 256) {
        int kc = i >> 9, c = i & 511;
        async16(Wq + (size_t)(c >> 2) * 128 + (kc << 5) + ((c & 3) << 3),
                Bb[0] + (kc << 12) + (c << 3));
    }

    // LN1 with inverse-roll gather: thread = (row = tid>>2, qtr = tid&3)
    {
        int row = tid >> 2, qtr = tid & 3;
        int r = bm + row;
        int b = r >> 12, rem = r & 4095;
        int wi = rem >> 6, n = rem & 63;
        int hp = ((wi >> 3) << 3) + (n >> 3);
        int wp = ((wi & 7) << 3) + (n & 7);
        int h = (hp + shift) & 63, w = (wp + shift) & 63;
        int src = (b << 12) + (h << 6) + w;
        const float* gr = g + (size_t)src * 128 + qtr * 32;
        float vals[32];
        float s1 = 0.f, s2 = 0.f;
        #pragma unroll
        for (int i = 0; i < 8; ++i) {
            float4 v4 = *(const float4*)(gr + i * 4);
            vals[i * 4] = v4.x; vals[i * 4 + 1] = v4.y;
            vals[i * 4 + 2] = v4.z; vals[i * 4 + 3] = v4.w;
            s1 += v4.x + v4.y + v4.z + v4.w;
            s2 += v4.x * v4.x + v4.y * v4.y + v4.z * v4.z + v4.w * v4.w;
        }
        s1 += __shfl_xor(s1, 1); s1 += __shfl_xor(s1, 2);
        s2 += __shfl_xor(s2, 1); s2 += __shfl_xor(s2, 2);
        float mu = s1 * (1.f / 128.f);
        float var = s2 * (1.f / 128.f) - mu * mu;
        float inv = rsqrtf(var + 1e-5f);
        #pragma unroll
        for (int i = 0; i < 32; ++i) {
            int c = qtr * 32 + i;
            float o = (vals[i] - mu) * inv * BF(wtb[O_N1G + d * 128 + c])
                      + BF(wtb[O_N1B + d * 128 + c]);
            Ach[qtr * CH_S + row * ROW_S + i] = FBu(o);
        }
    }
    __syncthreads();   // drains stage(0); Ach visible

    const f32x4 zero = {0.f, 0.f, 0.f, 0.f};
    f32x4 acc[2][4];
    for (int s = 0; s < 6; ++s) {
        const int nc = s >> 1, kh = s & 1;
        const int bsel = s & 1;
        if (s < 5) {   // issue next sub-tile stage first
            int t = s + 1, nct = t >> 1, kht = t & 1;
            const u16* Bg = Wq + nct * 16384;
            #pragma unroll
            for (int i = tid; i < 1024; i += 256) {
                int kc = i >> 9, c = i & 511;
                async16(Bg + (size_t)(c >> 2) * 128 + (kht << 6) + (kc << 5) + ((c & 3) << 3),
                        Bb[t & 1] + (kc << 12) + (c << 3));
            }
        }
        if (kh == 0) {
            #pragma unroll
            for (int i = 0; i < 2; ++i)
                #pragma unroll
                for (int j = 0; j < 4; ++j) acc[i][j] = zero;
        }
        #pragma unroll
        for (int kc = 0; kc < 2; ++kc) {
            bf16x8 af[2], bfr[4];
            #pragma unroll
            for (int t = 0; t < 2; ++t)
                af[t] = *(const bf16x8*)(Ach + (2 * kh + kc) * CH_S + (wm + (t << 4) + lr) * ROW_S + (q << 3));
            #pragma unroll
            for (int t = 0; t < 4; ++t)
                bfr[t] = *(const bf16x8*)(Bb[bsel] + (kc << 12) + ((wn + (t << 4) + lr) << 5) + (q << 3));
            #pragma unroll
            for (int mt = 0; mt < 2; ++mt)
                #pragma unroll
                for (int nt = 0; nt < 4; ++nt)
                    acc[mt][nt] = __builtin_amdgcn_mfma_f32_16x16x32_bf16(
                        af[mt], bfr[nt], acc[mt][nt], 0, 0, 0);
        }
        if (kh == 1) {   // epilogue for this nc
            #pragma unroll
            for (int nt = 0; nt < 4; ++nt) {
                int col = wn + (nt << 4) + lr;
                float bv = BF(wtb[O_QKVB + d * 384 + nc * 128 + col]);
                #pragma unroll
                for (int mt = 0; mt < 2; ++mt) {
                    #pragma unroll
                    for (int i = 0; i < 4; ++i) {
                        int r = bm + wm + (mt << 4) + (q << 2) + i;
                        qkv[(size_t)r * 384 + nc * 128 + col] = FBu(acc[mt][nt][i] + bv);
                    }
                }
            }
        }
        if (s < 5) __syncthreads();   // drains stage(s+1); frees Bb[bsel]
    }
}

// ---------------------------------------------------------------------------
// Windowed MFMA attention + FUSED output projection. Block = one window;
// attn phase: wave = one head (wave-private LDS, no barriers). Then each
// wave writes its O columns (bf16, proj-A chunk layout, row stride 36) into
// its OWN pbuf slice (reuse after P consumed), ONE barrier, and the proj
// phase (wave = 32-col block) computes O @ pw + pb with window-reverse/roll
// scatter-add into g. Math identical to the former gemm_mfma<3>; kills 2
// launches + 32 MB of Cbf traffic.
// ---------------------------------------------------------------------------
__launch_bounds__(256, 2)
__global__ void attn_k(const u16* __restrict__ qkv, const u16* __restrict__ wtu,
                       const bf16* __restrict__ wtb, float* __restrict__ g,
                       int d, int shift) {
    __shared__ __align__(16) u16 vT[4][32][72];    // V^T per head (padded)
    __shared__ __align__(16) u16 pbuf[4][4608];    // P bf16 / then O proj-A chunks
    const bf16* rp = wtb + O_RP + d * 900;
    const int wq = blockIdx.x;
    const int head = threadIdx.x >> 6;
    const int lane = threadIdx.x & 63;
    const int q8 = lane >> 4, lr = lane & 15;
    const size_t base = (size_t)wq * 64;
    const f32x4 zero = {0.f, 0.f, 0.f, 0.f};

    // stage V^T: thread=m-row, 4x bf16x8 global loads -> scattered u16 writes
    #pragma unroll
    for (int j = 0; j < 4; ++j) {
        bf16x8 vv = *(const bf16x8*)(qkv + (base + lane) * 384 + 256 + head * 32 + j * 8);
        #pragma unroll
        for (int e = 0; e < 8; ++e) vT[head][j * 8 + e][lane] = ((const u16*)&vv)[e];
    }

    // Q/K fragments direct from global (16B contiguous), S = Q K^T
    bf16x8 af[4], bfk[4];
    #pragma unroll
    for (int t = 0; t < 4; ++t) {
        af[t]  = *(const bf16x8*)(qkv + (base + t * 16 + lr) * 384 + head * 32 + q8 * 8);
        bfk[t] = *(const bf16x8*)(qkv + (base + t * 16 + lr) * 384 + 128 + head * 32 + q8 * 8);
    }
    f32x4 accs[4][4];
    #pragma unroll
    for (int rt = 0; rt < 4; ++rt)
        #pragma unroll
        for (int ct = 0; ct < 4; ++ct) accs[rt][ct] = zero;
    #pragma unroll
    for (int rt = 0; rt < 4; ++rt)
        #pragma unroll
        for (int ct = 0; ct < 4; ++ct)
            accs[rt][ct] = __builtin_amdgcn_mfma_f32_16x16x32_bf16(
                af[rt], bfk[ct], accs[rt][ct], 0, 0, 0);

    // scale + rel-pos bias + region mask + softmax + normalized bf16 P -> LDS
    const int wloc = wq & 63;
    const int wh = (wloc >> 3) << 3, wwb = (wloc & 7) << 3;
    #pragma unroll
    for (int rt = 0; rt < 4; ++rt) {
        #pragma unroll
        for (int i = 0; i < 4; ++i) {
            int r = rt * 16 + q8 * 4 + i;
            int ti = r >> 3, tj = r & 7;
            int regt = 0;
            if (shift) {
                int hp = wh + ti, wp = wwb + tj;
                int rh = hp < 56 ? 0 : (hp < 60 ? 1 : 2);
                int rw = wp < 56 ? 0 : (wp < 60 ? 1 : 2);
                regt = rh * 3 + rw;
            }
            float sv[4];
            float mx = -1e30f;
            #pragma unroll
            for (int ct = 0; ct < 4; ++ct) {
                int m = ct * 16 + lr;
                float a = accs[rt][ct][i] * 0.17677669529663687f;
                int idx = (ti - (m >> 3) + 7) * 15 + (tj - (m & 7) + 7);
                a += BF(rp[idx * 4 + head]);
                if (shift) {
                    int hp = wh + (m >> 3), wp = wwb + (m & 7);
                    int rh = hp < 56 ? 0 : (hp < 60 ? 1 : 2);
                    int rw = wp < 56 ? 0 : (wp < 60 ? 1 : 2);
                    if (regt != rh * 3 + rw) a -= 100.f;
                }
                sv[ct] = a;
                mx = fmaxf(mx, a);
            }
            mx = fmaxf(mx, __shfl_xor(mx, 1));
            mx = fmaxf(mx, __shfl_xor(mx, 2));
            mx = fmaxf(mx, __shfl_xor(mx, 4));
            mx = fmaxf(mx, __shfl_xor(mx, 8));
            float l = 0.f;
            #pragma unroll
            for (int ct = 0; ct < 4; ++ct) { sv[ct] = expf(sv[ct] - mx); l += sv[ct]; }
            l += __shfl_xor(l, 1); l += __shfl_xor(l, 2);
            l += __shfl_xor(l, 4); l += __shfl_xor(l, 8);
            float inv = 1.f / l;
            #pragma unroll
            for (int ct = 0; ct < 4; ++ct)
                pbuf[head][r * 72 + ct * 16 + lr] = FBu(sv[ct] * inv);
        }
    }

    // PV: O = P @ V  (A from pbuf rows, B from vT)
    f32x4 acco[4][2];
    #pragma unroll
    for (int rt = 0; rt < 4; ++rt) { acco[rt][0] = zero; acco[rt][1] = zero; }
    #pragma unroll
    for (int mh = 0; mh < 2; ++mh) {
        bf16x8 vb[2];
        #pragma unroll
        for (int dt = 0; dt < 2; ++dt)
            vb[dt] = *(const bf16x8*)(&vT[head][dt * 16 + lr][mh * 32 + q8 * 8]);
        #pragma unroll
        for (int rt = 0; rt < 4; ++rt) {
            bf16x8 pa = *(const bf16x8*)(&pbuf[head][(rt * 16 + lr) * 72 + mh * 32 + q8 * 8]);
            #pragma unroll
            for (int dt = 0; dt < 2; ++dt)
                acco[rt][dt] = __builtin_amdgcn_mfma_f32_16x16x32_bf16(
                    pa, vb[dt], acco[rt][dt], 0, 0, 0);
        }
    }

    // write O (bf16) into own pbuf slice as proj A-chunk: chunk=head holds
    // O cols [head*32, head*32+32), row stride 36 (bank-skewed, 16B-aligned)
    #pragma unroll
    for (int rt = 0; rt < 4; ++rt)
        #pragma unroll
        for (int dt = 0; dt < 2; ++dt)
            #pragma unroll
            for (int i = 0; i < 4; ++i) {
                int r = rt * 16 + q8 * 4 + i;
                pbuf[head][r * ROW_S + dt * 16 + lr] = FBu(acco[rt][dt][i]);
            }
    __syncthreads();

    // proj: C[64][128] = O @ pw^T + pb, scatter-add to g. wave = 32-col block.
    const u16* Wp = wtu + O_PW + d * 16384;
    const int wn = head << 5;
    f32x4 accp[4][2];
    #pragma unroll
    for (int rt = 0; rt < 4; ++rt) { accp[rt][0] = zero; accp[rt][1] = zero; }
    #pragma unroll
    for (int k0 = 0; k0 < 4; ++k0) {
        bf16x8 ap[4], bp[2];
        #pragma unroll
        for (int rt = 0; rt < 4; ++rt)
            ap[rt] = *(const bf16x8*)(&pbuf[k0][(rt * 16 + lr) * ROW_S + q8 * 8]);
        #pragma unroll
        for (int nt = 0; nt < 2; ++nt)
            bp[nt] = *(const bf16x8*)(Wp + (size_t)(wn + (nt << 4) + lr) * 128 + (k0 << 5) + (q8 << 3));
        #pragma unroll
        for (int rt = 0; rt < 4; ++rt)
            #pragma unroll
            for (int nt = 0; nt < 2; ++nt)
                accp[rt][nt] = __builtin_amdgcn_mfma_f32_16x16x32_bf16(
                    ap[rt], bp[nt], accp[rt][nt], 0, 0, 0);
    }
    #pragma unroll
    for (int nt = 0; nt < 2; ++nt) {
        int col = wn + (nt << 4) + lr;
        float bv = BF(wtb[O_PB + d * 128 + col]);
        #pragma unroll
        for (int rt = 0; rt < 4; ++rt) {
            #pragma unroll
            for (int i = 0; i < 4; ++i) {
                int r = (int)base + rt * 16 + q8 * 4 + i;
                float v = accp[rt][nt][i] + bv;
                int b = r >> 12, rem = r & 4095;
                int wi = rem >> 6, n = rem & 63;
                int hp = ((wi >> 3) << 3) + (n >> 3);
                int wp = ((wi & 7) << 3) + (n & 7);
                int h = (hp + shift) & 63, w = (wp + shift) & 63;
                g[((size_t)((b << 12) + (h << 6) + w)) * 128 + col] += v;
            }
        }
    }
}

// ---------------------------------------------------------------------------
// Fused MLP: LN2 + f1 + GELU + f2 + residual into g (+ bf16 copy to gbf).
// Block = 64 rows, 512 blocks. LDS: Ach | bufB1 16KB | bufB2 16KB | buf2.
// Pipeline: stage B1(0) before LN; per h: issue B2(h), compute MFMA1+GELU,
// barrier, issue B1(h+1), compute MFMA2, barrier. 2 barriers/h,
// stage latency hidden under compute.
// ---------------------------------------------------------------------------
__launch_bounds__(256)
__global__ void mlp_k(float* __restrict__ g, bf16* __restrict__ gbf,
                      const u16* __restrict__ wtu, const bf16* __restrict__ wtb,
                      int d) {
    __shared__ __align__(16) u16 Ach[4 * CH_S];
    __shared__ __align__(16) u16 bufB1[8192];
    __shared__ __align__(16) u16 bufB2[8192];
    __shared__ __align__(16) u16 buf2[2 * CH_S];
    const int tid = threadIdx.x;
    const int wave = tid >> 6, lane = tid & 63;
    const int q = lane >> 4, lr = lane & 15;
    const int wm = (wave >> 1) << 5;   // 0 / 32 (row split)
    const int wn0 = (wave & 1) << 5;   // stage1: 32-hcol split
    const int wn = (wave & 1) << 6;    // stage2: 64-ncol split
    const int bm = blockIdx.x << 6;

    // prologue stage: B1 chunk h=0 (hides under LN's global loads)
    {
        const u16* B1g = wtu + O_F1W + d * 65536;
        #pragma unroll
        for (int i = tid; i < 1024; i += 256) {
            int kc = i >> 8, c = i & 255;
            async16(B1g + (c >> 2) * 128 + (kc << 5) + ((c & 3) << 3),
                    bufB1 + (kc << 11) + (c << 3));
        }
    }

    // LN2: thread = (row = tid>>2, qtr = tid&3)
    {
        int row = tid >> 2, qtr = tid & 3;
        const float* gr = g + (size_t)(bm + row) * 128 + qtr * 32;
        float vals[32];
        float s1 = 0.f, s2 = 0.f;
        #pragma unroll
        for (int i = 0; i < 8; ++i) {
            float4 v4 = *(const float4*)(gr + i * 4);
            vals[i * 4] = v4.x; vals[i * 4 + 1] = v4.y;
            vals[i * 4 + 2] = v4.z; vals[i * 4 + 3] = v4.w;
            s1 += v4.x + v4.y + v4.z + v4.w;
            s2 += v4.x * v4.x + v4.y * v4.y + v4.z * v4.z + v4.w * v4.w;
        }
        s1 += __shfl_xor(s1, 1); s1 += __shfl_xor(s1, 2);
        s2 += __shfl_xor(s2, 1); s2 += __shfl_xor(s2, 2);
        float mu = s1 * (1.f / 128.f);
        float var = s2 * (1.f / 128.f) - mu * mu;
        float inv = rsqrtf(var + 1e-5f);
        #pragma unroll
        for (int i = 0; i < 32; ++i) {
            int c = qtr * 32 + i;
            float o = (vals[i] - mu) * inv * BF(wtb[O_N2G + d * 128 + c])
                      + BF(wtb[O_N2B + d * 128 + c]);
            Ach[qtr * CH_S + row * ROW_S + i] = FBu(o);
        }
    }
    __syncthreads();   // drains B1(0); Ach visible

    const f32x4 zero = {0.f, 0.f, 0.f, 0.f};
    f32x4 acc2[2][4];
    #pragma unroll
    for (int i = 0; i < 2; ++i)
        #pragma unroll
        for (int j = 0; j < 4; ++j) acc2[i][j] = zero;

    for (int h = 0; h < 8; ++h) {
        // issue B2(h) stage first (hides under MFMA1 + GELU)
        {
            const u16* B2g = wtu + O_F2W + d * 65536 + h * 64;
            #pragma unroll
            for (int i = tid; i < 1024; i += 256) {
                int kc = i >> 9, c = i & 511;
                async16(B2g + (size_t)(c >> 2) * 512 + (kc << 5) + ((c & 3) << 3),
                        bufB2 + (kc << 12) + (c << 3));
            }
        }
        // MFMA1 from Ach x bufB1 (B1(h), ready from previous barrier)
        f32x4 acc1[2][2];
        #pragma unroll
        for (int i = 0; i < 2; ++i) { acc1[i][0] = zero; acc1[i][1] = zero; }
        #pragma unroll
        for (int k0 = 0; k0 < 4; ++k0) {
            bf16x8 af[2], bfr[2];
            #pragma unroll
            for (int t = 0; t < 2; ++t) {
                af[t]  = *(const bf16x8*)(Ach + k0 * CH_S + (wm + (t << 4) + lr) * ROW_S + (q << 3));
                bfr[t] = *(const bf16x8*)(bufB1 + (k0 << 11) + ((wn0 + (t << 4) + lr) << 5) + (q << 3));
            }
            #pragma unroll
            for (int mt = 0; mt < 2; ++mt)
                #pragma unroll
                for (int nt = 0; nt < 2; ++nt)
                    acc1[mt][nt] = __builtin_amdgcn_mfma_f32_16x16x32_bf16(
                        af[mt], bfr[nt], acc1[mt][nt], 0, 0, 0);
        }
        // GELU -> hidden chunks (padded) in buf2
        #pragma unroll
        for (int nt = 0; nt < 2; ++nt) {
            int c = wn0 + (nt << 4) + lr;
            float hb = BF(wtb[O_F1B + d * 512 + h * 64 + c]);
            #pragma unroll
            for (int mt = 0; mt < 2; ++mt) {
                #pragma unroll
                for (int i = 0; i < 4; ++i) {
                    int r = wm + (mt << 4) + (q << 2) + i;
                    float v = acc1[mt][nt][i] + hb;
                    float ge = 0.5f * v * (1.0f + erff(v * 0.70710678118654752f));
                    buf2[(c >> 5) * CH_S + r * ROW_S + (c & 31)] = FBu(ge);
                }
            }
        }
        __syncthreads();   // drains B2(h); buf2 visible; bufB1 free
        // issue B1(h+1) stage (hides under MFMA2)
        if (h < 7) {
            const u16* B1g = wtu + O_F1W + d * 65536 + (h + 1) * 8192;
            #pragma unroll
            for (int i = tid; i < 1024; i += 256) {
                int kc = i >> 8, c = i & 255;
                async16(B1g + (c >> 2) * 128 + (kc << 5) + ((c & 3) << 3),
                        bufB1 + (kc << 11) + (c << 3));
            }
        }
        // MFMA2 from buf2 x bufB2
        #pragma unroll
        for (int kc = 0; kc < 2; ++kc) {
            bf16x8 ah[2], b2[4];
            #pragma unroll
            for (int t = 0; t < 2; ++t)
                ah[t] = *(const bf16x8*)(buf2 + kc * CH_S + (wm + (t << 4) + lr) * ROW_S + (q << 3));
            #pragma unroll
            for (int t = 0; t < 4; ++t)
                b2[t] = *(const bf16x8*)(bufB2 + (kc << 12) + ((wn + (t << 4) + lr) << 5) + (q << 3));
            #pragma unroll
            for (int mt = 0; mt < 2; ++mt)
                #pragma unroll
                for (int nt = 0; nt < 4; ++nt)
                    acc2[mt][nt] = __builtin_amdgcn_mfma_f32_16x16x32_bf16(
                        ah[mt], b2[nt], acc2[mt][nt], 0, 0, 0);
        }
        __syncthreads();   // drains B1(h+1); bufB2/buf2 free
    }
    #pragma unroll
    for (int nt = 0; nt < 4; ++nt) {
        int col = wn + (nt << 4) + lr;
        float bv = BF(wtb[O_F2B + d * 128 + col]);
        #pragma unroll
        for (int mt = 0; mt < 2; ++mt) {
            #pragma unroll
            for (int i = 0; i < 4; ++i) {
                int r = bm + wm + (mt << 4) + (q << 2) + i;
                size_t idx = (size_t)r * 128 + col;
                float nv = g[idx] + acc2[mt][nt][i] + bv;
                g[idx] = nv;
                gbf[idx] = FB(nv);
            }
        }
    }
}

// ---------------------------------------------------------------------------
// Fused fusion chain + LSTM gate -> out. 32-row tiles, 1024 blocks
// (4 blocks/CU). GEMM operands direct from global; ReLU intermediate in
// padded LDS (4 chunks of [32][36], +16 skew). 1 barrier total.
// ---------------------------------------------------------------------------
__launch_bounds__(256, 4)
__global__ void fuse3_k(const u16* __restrict__ Aloc, const u16* __restrict__ Ag,
                        const u16* __restrict__ wtu, const bf16* __restrict__ wtb,
                        const void* __restrict__ cx, void* __restrict__ out,
                        const void* __restrict__ dtp) {
    __shared__ __align__(16) u16 relb[4 * CH32_S];
    const int mode = get_mode(dtp);
    const int tid = threadIdx.x;
    const int wave = tid >> 6, lane = tid & 63;
    const int q = lane >> 4, lr = lane & 15;
    const int wn = wave << 5;          // 4 waves x 32-col split
    const int bm = blockIdx.x << 5;    // 32-row tile
    const f32x4 zero = {0.f, 0.f, 0.f, 0.f};
    f32x4 acc1[2][2], acc2[2][2];
    #pragma unroll
    for (int i = 0; i < 2; ++i)
        #pragma unroll
        for (int j = 0; j < 2; ++j) { acc1[i][j] = zero; acc2[i][j] = zero; }

    #pragma unroll
    for (int k0 = 0; k0 < 4; ++k0) {
        bf16x8 al[2], ag[2], blf[2], bgf[2];
        #pragma unroll
        for (int t = 0; t < 2; ++t) {
            size_t off = (size_t)(bm + (t << 4) + lr) * 128 + (k0 << 5) + (q << 3);
            al[t] = *(const bf16x8*)(Aloc + off);
            ag[t] = *(const bf16x8*)(Ag + off);
        }
        #pragma unroll
        for (int t = 0; t < 2; ++t) {
            int woff = ((wn + (t << 4) + lr) << 7) + (k0 << 5) + (q << 3);
            blf[t] = *(const bf16x8*)(wtu + O_LFW + woff);
            bgf[t] = *(const bf16x8*)(wtu + O_GFW + woff);
        }
        #pragma unroll
        for (int mt = 0; mt < 2; ++mt)
            #pragma unroll
            for (int nt = 0; nt < 2; ++nt) {
                acc1[mt][nt] = __builtin_amdgcn_mfma_f32_16x16x32_bf16(
                    al[mt], blf[nt], acc1[mt][nt], 0, 0, 0);
                acc2[mt][nt] = __builtin_amdgcn_mfma_f32_16x16x32_bf16(
                    ag[mt], bgf[nt], acc2[mt][nt], 0, 0, 0);
            }
    }
    // relu((local@lf + lfb) * (g@gf + gfb)) -> padded LDS (chunk = wave)
    #pragma unroll
    for (int nt = 0; nt < 2; ++nt) {
        int c = wn + (nt << 4) + lr;
        float lfb = BF(wtb[O_LFB + c]);
        float gfb = BF(wtb[O_GFB + c]);
        #pragma unroll
        for (int mt = 0; mt < 2; ++mt) {
            #pragma unroll
            for (int i = 0; i < 4; ++i) {
                int r = (mt << 4) + (q << 2) + i;
                float t1 = acc1[mt][nt][i] + lfb;
                float t2 = acc2[mt][nt][i] + gfb;
                float rel = t1 * t2;
                relb[(c >> 5) * CH32_S + r * ROW_S + (c & 31)] = FBu(rel > 0.f ? rel : 0.f);
            }
        }
    }
    __syncthreads();
    f32x4 acc3[2][2];
    #pragma unroll
    for (int i = 0; i < 2; ++i)
        #pragma unroll
        for (int j = 0; j < 2; ++j) acc3[i][j] = zero;
    #pragma unroll
    for (int k0 = 0; k0 < 4; ++k0) {
        bf16x8 ar[2], bff[2];
        #pragma unroll
        for (int t = 0; t < 2; ++t)
            ar[t] = *(const bf16x8*)(relb + k0 * CH32_S + ((t << 4) + lr) * ROW_S + (q << 3));
        #pragma unroll
        for (int t = 0; t < 2; ++t)
            bff[t] = *(const bf16x8*)(wtu + O_FFW + ((wn + (t << 4) + lr) << 7) + (k0 << 5) + (q << 3));
        #pragma unroll
        for (int mt = 0; mt < 2; ++mt)
            #pragma unroll
            for (int nt = 0; nt < 2; ++nt)
                acc3[mt][nt] = __builtin_amdgcn_mfma_f32_16x16x32_bf16(
                    ar[mt], bff[nt], acc3[mt][nt], 0, 0, 0);
    }
    // LSTM gating epilogue
    #pragma unroll
    for (int nt = 0; nt < 2; ++nt) {
        int col = wn + (nt << 4) + lr;
        float ffb = BF(wtb[O_FFB + col]);
        #pragma unroll
        for (int mt = 0; mt < 2; ++mt) {
            #pragma unroll
            for (int i = 0; i < 4; ++i) {
                int r = bm + (mt << 4) + (q << 2) + i;
                size_t idx = (size_t)r * 128 + col;
                float v = acc3[mt][nt][i] + ffb;
                float gate = 1.f / (1.f + expf(-v));
                float cell = tanhf(v);
                float cy = gate * (LD(cx, idx, mode) + cell);
                float hy = gate * tanhf(cy);
                if (mode) ((float*)out)[idx] = hy;
                else      ((bf16*)out)[idx] = FB(hy);
            }
        }
    }
}

// ---------------------------------------------------------------------------
// Deformable conv1d, stage 1: offset/mask conv. One WAVE per output position.
// ---------------------------------------------------------------------------
__launch_bounds__(256)
__global__ void offmask_k(const void* __restrict__ xt, const bf16* __restrict__ wtb,
                          float4* __restrict__ om) {
    const int mode = get_mode(xt);
    const int wave = threadIdx.x >> 6, lane = threadIdx.x & 63;
    const int gl = blockIdx.x * 4 + wave;
    const int b = gl >> 12, l = gl & 4095;
    float wo[3][3][2], wmk[3][3][2];
    #pragma unroll
    for (int k = 0; k < 3; ++k)
        #pragma unroll
        for (int j = 0; j < 3; ++j) {
            wo[k][j][0]  = BF(wtb[O_OW + (k * 128 + lane) * 3 + j]);
            wo[k][j][1]  = BF(wtb[O_OW + (k * 128 + lane + 64) * 3 + j]);
            wmk[k][j][0] = BF(wtb[O_MW + (k * 128 + lane) * 3 + j]);
            wmk[k][j][1] = BF(wtb[O_MW + (k * 128 + lane + 64) * 3 + j]);
        }
    float a6[6] = {};
    #pragma unroll
    for (int j = 0; j < 3; ++j) {
        int row = l + j - 1;
        if (row >= 0 && row < 4096) {
            size_t base = ((size_t)(b << 12) + row) * 128;
            float x0 = LD(xt, base + lane, mode);
            float x1 = LD(xt, base + lane + 64, mode);
            #pragma unroll
            for (int k = 0; k < 3; ++k) {
                a6[k]     += x0 * wo[k][j][0]  + x1 * wo[k][j][1];
                a6[3 + k] += x0 * wmk[k][j][0] + x1 * wmk[k][j][1];
            }
        }
    }
    #pragma unroll
    for (int off = 32; off > 0; off >>= 1)
        #pragma unroll
        for (int k = 0; k < 6; ++k) a6[k] += __shfl_down(a6[k], off);
    if (lane == 0) {
        #pragma unroll
        for (int k = 0; k < 3; ++k) {
            float off = a6[k] + BF(wtb[O_OB + k]);
            float pos = fminf(fmaxf((float)l + off, 0.f), 4095.f);
            float fpf = floorf(pos);
            float mv = a6[3 + k] + BF(wtb[O_MB + k]);
            float mk = 1.f / (1.f + expf(-mv));
            om[(size_t)gl * 3 + k] = make_float4(fpf, pos - fpf, mk, 0.f);
        }
    }
}

// ---------------------------------------------------------------------------
// Deformable conv1d, stage 2: sampling + transpose to (B,C,L) bf16.
// ---------------------------------------------------------------------------
__launch_bounds__(512)
__global__ void sample_k(const void* __restrict__ xt, const float4* __restrict__ om,
                         bf16* __restrict__ outL) {
    __shared__ __align__(16) u16 ot[128 * 72];
    const int mode = get_mode(xt);
    const int tid = threadIdx.x;
    const int b = blockIdx.x >> 6;
    const int l0 = (blockIdx.x & 63) << 6;
    const int c = tid & 127, lh = tid >> 7;
    for (int it = 0; it < 16; ++it) {
        int l_loc = lh * 16 + it;
        size_t gl = (size_t)(b << 12) + l0 + l_loc;
        float o = 0.f;
        #pragma unroll
        for (int k = 0; k < 3; ++k) {
            float4 v = om[gl * 3 + k];
            int fp = (int)v.x;
            int cp = fp + 1 > 4095 ? 4095 : fp + 1;
            float al = v.y, mk = v.z;
            float xf = LD(xt, ((size_t)(b << 12) + fp) * 128 + c, mode);
            float xc = LD(xt, ((size_t)(b << 12) + cp) * 128 + c, mode);
            o += (xf * (1.f - al) + xc * al) * mk;
        }
        ot[c * 72 + l_loc] = FBu(o);
    }
    __syncthreads();
    #pragma unroll
    for (int pass = 0; pass < 2; ++pass) {
        int cc = pass * 64 + (tid >> 3);
        int oo = tid & 7;
        const uint4 v = *(const uint4*)(ot + cc * 72 + oo * 8);
        *(uint4*)(outL + (size_t)b * 524288 + (size_t)cc * 4096 + l0 + oo * 8) = v;
    }
}

extern "C" void kernel_launch(void* const* d_in, const int* in_sizes, int n_in,
                              void* d_out, int out_size, void* d_ws, size_t ws_size,
                              hipStream_t stream) {
    (void)out_size; (void)ws_size;
    int I[28] = {0,1,2,3,4,5,6,7,8,9,10,11,12,13,14,15,16,17,18,19,20,21,22,23,24,25,26,27};
    if (n_in >= 28 && in_sizes[7] != 98304 && in_sizes[23] == 98304 && in_sizes[26] == 1800) {
        int alt[28] = {27, 9, 0, 25, 24, 15, 14, 23, 22, 26, 21, 20, 17, 16,
                       2, 1, 4, 3, 19, 18, 13, 12, 11, 10, 8, 7, 6, 5};
        for (int i = 0; i < 28; ++i) I[i] = alt[i];
    }
    const void* xt = d_in[I[0]];
    const void* hx = d_in[I[1]];
    const void* cx = d_in[I[2]];

    char* wsb = (char*)d_ws;
    float* g    = (float*)wsb;                    // fp32 residual [0,16M)
    u16*   Abf  = (u16*)(wsb + 16777216);         // bf16(g)
    u16*   Bbf  = (u16*)(wsb + 25165824);         // Xcat / qkv
    u16*   Cbf  = (u16*)(wsb + 50331648);         // local branch
    bf16*  wtb  = (bf16*)(wsb + 58720256);
    u16*   wtu  = (u16*)wtb;
    float4* om  = (float4*)(wsb + 25165824);      // reuses Bbf after last attn

    Prep p;
    PrepT descs[29] = {
        {d_in[I[3]],  0,     256, 128, O_REDW},
        {d_in[I[7]],  0,     128, 384, O_QKVW},
        {d_in[I[7]],  49152, 128, 384, O_QKVW + 49152},
        {d_in[I[10]], 0,     128, 128, O_PW},
        {d_in[I[10]], 16384, 128, 128, O_PW + 16384},
        {d_in[I[14]], 0,     128, 512, O_F1W},
        {d_in[I[14]], 65536, 128, 512, O_F1W + 65536},
        {d_in[I[16]], 0,     512, 128, O_F2W},
        {d_in[I[16]], 65536, 512, 128, O_F2W + 65536},
        {d_in[I[22]], 0,     128, 128, O_LFW},
        {d_in[I[24]], 0,     128, 128, O_GFW},
        {d_in[I[26]], 0,     128, 128, O_FFW},
        {d_in[I[4]],  0,  128, 0, O_REDB},
        {d_in[I[8]],  0,  768, 0, O_QKVB},
        {d_in[I[11]], 0,  256, 0, O_PB},
        {d_in[I[15]], 0, 1024, 0, O_F1B},
        {d_in[I[17]], 0,  256, 0, O_F2B},
        {d_in[I[23]], 0,  128, 0, O_LFB},
        {d_in[I[25]], 0,  128, 0, O_GFB},
        {d_in[I[27]], 0,  128, 0, O_FFB},
        {d_in[I[9]],  0, 1800, 0, O_RP},
        {d_in[I[5]],  0,  256, 0, O_N1G},
        {d_in[I[6]],  0,  256, 0, O_N1B},
        {d_in[I[12]], 0,  256, 0, O_N2G},
        {d_in[I[13]], 0,  256, 0, O_N2B},
        {d_in[I[18]], 0, 1152, 0, O_OW},
        {d_in[I[19]], 0,    3, 0, O_OB},
        {d_in[I[20]], 0, 1152, 0, O_MW},
        {d_in[I[21]], 0,    3, 0, O_MB},
    };
    int cum = 0;
    for (int i = 0; i < 29; ++i) {
        p.d[i] = descs[i];
        p.start[i] = cum;
        cum += (descs[i].N > 0) ? descs[i].K * descs[i].N : descs[i].K;
    }
    p.start[29] = cum;

    prep_k<<<(cum + 255) / 256, 256, 0, stream>>>(p, wtb, xt);
    xcat_k<<<1024, 256, 0, stream>>>(xt, hx, Bbf);

    // g = Xcat @ red_w + red_b (fp32)
    gemm_mfma<5><<<dim3(1, 512), 256, 0, stream>>>(Bbf, wtu + O_REDW, wtb + O_REDB,
                                                   nullptr, g, 32768, 128, 256, 0);

    for (int d = 0; d < 2; ++d) {
        int shift = d ? 4 : 0;
        qkvln_k<<<512, 256, 0, stream>>>(g, wtu, wtb, Bbf, d, shift);
        attn_k<<<512, 256, 0, stream>>>(Bbf, wtu, wtb, g, d, shift);
        mlp_k<<<512, 256, 0, stream>>>(g, (bf16*)Abf, wtu, wtb, d);
    }

    // local branch: offset/mask conv (wave-per-l), then sampling -> Cbf (B,C,L)
    offmask_k<<<8192, 256, 0, stream>>>(xt, wtb, om);
    sample_k<<<512, 512, 0, stream>>>(xt, om, (bf16*)Cbf);
    // fused fusion chain + LSTM -> out
    fuse3_k<<<1024, 256, 0, stream>>>(Cbf, Abf, wtu, wtb, cx, d_out, xt);
}

// Round 7
// 394.964 us; speedup vs baseline: 1.3690x; 1.0170x over previous
//
#include <hip/hip_runtime.h>
#include <hip/hip_bf16.h>
#include <math.h>

typedef __hip_bfloat16 bf16;
typedef unsigned short u16;
#define BF(x) __bfloat162float(x)
static __device__ __forceinline__ bf16 FB(float x) { return __float2bfloat16(x); }
static __device__ __forceinline__ u16 FBu(float x) {
    bf16 b = __float2bfloat16(x);
    return *(u16*)&b;
}

typedef __attribute__((ext_vector_type(4))) float f32x4;
typedef __attribute__((ext_vector_type(8))) __bf16 bf16x8;

// Problem: B=8, H=W=64, C=128, L=4096, NH=4, HD=32, WIN=8, N=64, NW=64, M=32768.

// Wt (prepped bf16 weights) element offsets
#define O_REDW 0
#define O_QKVW 32768
#define O_PW   131072
#define O_F1W  163840
#define O_F2W  294912
#define O_LFW  425984
#define O_GFW  442368
#define O_FFW  458752
#define O_REDB 475136
#define O_QKVB 475264
#define O_PB   476032
#define O_F1B  476288
#define O_F2B  477312
#define O_LFB  477568
#define O_GFB  477696
#define O_FFB  477824
#define O_RP   477952
#define O_N1G  479752
#define O_N1B  480008
#define O_N2G  480264
#define O_N2B  480520
#define O_OW   480776
#define O_OB   481928
#define O_MW   481931
#define O_MB   483083

// Padded LDS tile geometry for VALU-written A-tiles (kills 16-way conflicts):
// row stride 36 u16 (72 B = 18 banks), chunk stride 2320 u16 (64-row chunks).
#define ROW_S 36
#define CH_S  2320
// 32-row chunk variant (fuse3): 32*36 + 16 skew
#define CH32_S 1168

// Runtime input-dtype detection from xt (N(0,1) data). 0 = bf16, 1 = fp32.
__device__ __forceinline__ int get_mode(const void* xt) {
    const unsigned* w = (const unsigned*)xt;
    int zlo = 0, inband = 0;
    #pragma unroll
    for (int i = 0; i < 32; ++i) {
        unsigned lo = w[i] & 0xFFFFu;
        int e = (int)((lo >> 7) & 0xFF);
        zlo += (lo == 0u || lo == 0x8000u);
        inband += (e >= 100 && e <= 140);
    }
    if (zlo >= 29) return 1;
    return (inband >= 20) ? 0 : 1;
}

__device__ __forceinline__ float LD(const void* p, size_t i, int mode) {
    return mode ? ((const float*)p)[i] : BF(((const bf16*)p)[i]);
}

// async global->LDS, 16 bytes per lane
__device__ __forceinline__ void async16(const u16* g, u16* l) {
    __builtin_amdgcn_global_load_lds(
        (const __attribute__((address_space(1))) unsigned int*)g,
        (__attribute__((address_space(3))) unsigned int*)l, 16, 0, 0);
}

// ---------------------------------------------------------------------------
// Prep: transpose weights to [N][K] bf16 + convert params.
// ---------------------------------------------------------------------------
struct PrepT { const void* src; int srcOff, K, N, dstOff; };
struct Prep { PrepT d[29]; int start[30]; };

__global__ void prep_k(Prep p, bf16* __restrict__ dst, const void* __restrict__ dtp) {
    const int mode = get_mode(dtp);
    int i = blockIdx.x * 256 + threadIdx.x;
    if (i >= p.start[29]) return;
    int s = 0;
    while (p.start[s + 1] <= i) ++s;
    int e = i - p.start[s];
    float v;
    if (p.d[s].N > 0) {
        int n = e / p.d[s].K, k = e % p.d[s].K;
        v = LD(p.d[s].src, (size_t)p.d[s].srcOff + (size_t)k * p.d[s].N + n, mode);
    } else {
        v = LD(p.d[s].src, (size_t)p.d[s].srcOff + e, mode);
    }
    dst[p.d[s].dstOff + e] = FB(v);
}

// ---------------------------------------------------------------------------
// Fused concat + reduction GEMM: g = [xt|hx] @ red_w + red_b (fp32 out).
// 64x128 tile, 512 blocks (2/CU), BK=32, 8 k-tiles. B (red_w [128][256])
// staged via async16 double-buffer. A staged from xt (k<128) / hx (k>=128):
// bf16 mode = async16 direct; fp32 mode = T14 reg-stage split (issue loads
// for tile i+1, MFMA(i) hides latency, convert+ds_write into free buffer).
// Values bit-identical to the former xcat_k + gemm_mfma<5> pair.
// ---------------------------------------------------------------------------
__launch_bounds__(256)
__global__ void redgemm_k(const void* __restrict__ xt, const void* __restrict__ hx,
                          const u16* __restrict__ Bt, const bf16* __restrict__ bias,
                          float* __restrict__ outf) {
    __shared__ __align__(16) u16 Als[2][2048];   // 64 rows x 32 k
    __shared__ __align__(16) u16 Bls[2][4096];   // 128 rows x 32 k
    const int mode = get_mode(xt);
    const int tid = threadIdx.x;
    const int wave = tid >> 6, lane = tid & 63;
    const int q = lane >> 4, lr = lane & 15;
    const int wm = (wave >> 1) << 5, wn = (wave & 1) << 6;
    const int bm = blockIdx.x << 6;
    const int K = 256;
    const f32x4 zero = {0.f, 0.f, 0.f, 0.f};
    f32x4 acc[2][4];
    #pragma unroll
    for (int i = 0; i < 2; ++i)
        #pragma unroll
        for (int j = 0; j < 4; ++j) acc[i][j] = zero;

    const int arow = bm + (tid >> 2);     // tile row this thread stages
    const int ksub = (tid & 3) << 3;      // k offset within 32-wide tile

    if (mode) {
        // fp32 input: reg-stage A (load float4 x2 -> cvt bf16 -> ds_write 16B)
        float av[8];
        {
            const float* s = (const float*)xt + (size_t)arow * 128 + ksub;
            float4 a = *(const float4*)s; float4 b = *(const float4*)(s + 4);
            av[0]=a.x; av[1]=a.y; av[2]=a.z; av[3]=a.w;
            av[4]=b.x; av[5]=b.y; av[6]=b.z; av[7]=b.w;
            #pragma unroll
            for (int c2 = tid; c2 < 512; c2 += 256)
                async16(Bt + (size_t)(c2 >> 2) * K + ((c2 & 3) << 3), Bls[0] + (c2 << 3));
            u16 o[8];
            #pragma unroll
            for (int e = 0; e < 8; ++e) o[e] = FBu(av[e]);
            *(uint4*)(Als[0] + (tid << 3)) = *(const uint4*)o;
        }
        __syncthreads();
        for (int i = 0; i < 8; ++i) {
            const int cur = i & 1, nxt = cur ^ 1;
            float nv[8];
            if (i < 7) {
                int k1 = (i + 1) << 5;
                const float* s = (const float*)(k1 < 128 ? xt : hx)
                                 + (size_t)arow * 128 + (k1 & 127) + ksub;
                float4 a = *(const float4*)s; float4 b = *(const float4*)(s + 4);
                nv[0]=a.x; nv[1]=a.y; nv[2]=a.z; nv[3]=a.w;
                nv[4]=b.x; nv[5]=b.y; nv[6]=b.z; nv[7]=b.w;
                #pragma unroll
                for (int c2 = tid; c2 < 512; c2 += 256)
                    async16(Bt + (size_t)(c2 >> 2) * K + k1 + ((c2 & 3) << 3),
                            Bls[nxt] + (c2 << 3));
            }
            bf16x8 af[2], bfr[4];
            #pragma unroll
            for (int t = 0; t < 2; ++t)
                af[t] = *(const bf16x8*)(Als[cur] + ((wm + (t << 4) + lr) << 5) + (q << 3));
            #pragma unroll
            for (int t = 0; t < 4; ++t)
                bfr[t] = *(const bf16x8*)(Bls[cur] + ((wn + (t << 4) + lr) << 5) + (q << 3));
            #pragma unroll
            for (int mt = 0; mt < 2; ++mt)
                #pragma unroll
                for (int nt = 0; nt < 4; ++nt)
                    acc[mt][nt] = __builtin_amdgcn_mfma_f32_16x16x32_bf16(
                        af[mt], bfr[nt], acc[mt][nt], 0, 0, 0);
            if (i < 7) {
                u16 o[8];
                #pragma unroll
                for (int e = 0; e < 8; ++e) o[e] = FBu(nv[e]);
                *(uint4*)(Als[nxt] + (tid << 3)) = *(const uint4*)o;
            }
            __syncthreads();
        }
    } else {
        // bf16 input: async16 A directly from xt/hx (raw copy == xcat path)
        {
            async16((const u16*)xt + (size_t)arow * 128 + ksub, Als[0] + (tid << 3));
            #pragma unroll
            for (int c2 = tid; c2 < 512; c2 += 256)
                async16(Bt + (size_t)(c2 >> 2) * K + ((c2 & 3) << 3), Bls[0] + (c2 << 3));
        }
        __syncthreads();
        for (int i = 0; i < 8; ++i) {
            const int cur = i & 1, nxt = cur ^ 1;
            if (i < 7) {
                int k1 = (i + 1) << 5;
                const u16* s = (const u16*)(k1 < 128 ? xt : hx)
                               + (size_t)arow * 128 + (k1 & 127) + ksub;
                async16(s, Als[nxt] + (tid << 3));
                #pragma unroll
                for (int c2 = tid; c2 < 512; c2 += 256)
                    async16(Bt + (size_t)(c2 >> 2) * K + k1 + ((c2 & 3) << 3),
                            Bls[nxt] + (c2 << 3));
            }
            bf16x8 af[2], bfr[4];
            #pragma unroll
            for (int t = 0; t < 2; ++t)
                af[t] = *(const bf16x8*)(Als[cur] + ((wm + (t << 4) + lr) << 5) + (q << 3));
            #pragma unroll
            for (int t = 0; t < 4; ++t)
                bfr[t] = *(const bf16x8*)(Bls[cur] + ((wn + (t << 4) + lr) << 5) + (q << 3));
            #pragma unroll
            for (int mt = 0; mt < 2; ++mt)
                #pragma unroll
                for (int nt = 0; nt < 4; ++nt)
                    acc[mt][nt] = __builtin_amdgcn_mfma_f32_16x16x32_bf16(
                        af[mt], bfr[nt], acc[mt][nt], 0, 0, 0);
            __syncthreads();
        }
    }

    #pragma unroll
    for (int nt = 0; nt < 4; ++nt) {
        int col = wn + (nt << 4) + lr;
        float bv = BF(bias[col]);
        #pragma unroll
        for (int mt = 0; mt < 2; ++mt) {
            int row0 = bm + wm + (mt << 4) + (q << 2);
            #pragma unroll
            for (int i = 0; i < 4; ++i)
                outf[(size_t)(row0 + i) * 128 + col] = acc[mt][nt][i] + bv;
        }
    }
}

// ---------------------------------------------------------------------------
// Fused LN1 (+roll+window gather) + QKV GEMM. Block = 64 windowed rows,
// 512 blocks. LDS: Ach 4x[64][36] padded | Bb double-buffered 2x16KB.
// Pipeline: 6 half-K sub-tiles (nc x khalf); stage(s+1) issued before
// compute(s); stage(0) issued before the LN so it hides under LN's loads.
// ---------------------------------------------------------------------------
__launch_bounds__(256)
__global__ void qkvln_k(const float* __restrict__ g, const u16* __restrict__ wtu,
                        const bf16* __restrict__ wtb, u16* __restrict__ qkv,
                        int d, int shift) {
    __shared__ __align__(16) u16 Ach[4 * CH_S];
    __shared__ __align__(16) u16 Bb[2][8192];
    const int tid = threadIdx.x;
    const int wave = tid >> 6, lane = tid & 63;
    const int q = lane >> 4, lr = lane & 15;
    const int wm = (wave >> 1) << 5, wn = (wave & 1) << 6;
    const int bm = blockIdx.x << 6;
    const u16* Wq = wtu + O_QKVW + d * 49152;

    // prologue stage: sub-tile 0 (nc=0, khalf=0) into Bb[0]
    #pragma unroll
    for (int i = tid; i < 1024; i += 256) {
        int kc = i >> 9, c = i & 511;
        async16(Wq + (size_t)(c >> 2) * 128 + (kc << 5) + ((c & 3) << 3),
                Bb[0] + (kc << 12) + (c << 3));
    }

    // LN1 with inverse-roll gather: thread = (row = tid>>2, qtr = tid&3)
    {
        int row = tid >> 2, qtr = tid & 3;
        int r = bm + row;
        int b = r >> 12, rem = r & 4095;
        int wi = rem >> 6, n = rem & 63;
        int hp = ((wi >> 3) << 3) + (n >> 3);
        int wp = ((wi & 7) << 3) + (n & 7);
        int h = (hp + shift) & 63, w = (wp + shift) & 63;
        int src = (b << 12) + (h << 6) + w;
        const float* gr = g + (size_t)src * 128 + qtr * 32;
        float vals[32];
        float s1 = 0.f, s2 = 0.f;
        #pragma unroll
        for (int i = 0; i < 8; ++i) {
            float4 v4 = *(const float4*)(gr + i * 4);
            vals[i * 4] = v4.x; vals[i * 4 + 1] = v4.y;
            vals[i * 4 + 2] = v4.z; vals[i * 4 + 3] = v4.w;
            s1 += v4.x + v4.y + v4.z + v4.w;
            s2 += v4.x * v4.x + v4.y * v4.y + v4.z * v4.z + v4.w * v4.w;
        }
        s1 += __shfl_xor(s1, 1); s1 += __shfl_xor(s1, 2);
        s2 += __shfl_xor(s2, 1); s2 += __shfl_xor(s2, 2);
        float mu = s1 * (1.f / 128.f);
        float var = s2 * (1.f / 128.f) - mu * mu;
        float inv = rsqrtf(var + 1e-5f);
        #pragma unroll
        for (int i = 0; i < 32; ++i) {
            int c = qtr * 32 + i;
            float o = (vals[i] - mu) * inv * BF(wtb[O_N1G + d * 128 + c])
                      + BF(wtb[O_N1B + d * 128 + c]);
            Ach[qtr * CH_S + row * ROW_S + i] = FBu(o);
        }
    }
    __syncthreads();   // drains stage(0); Ach visible

    const f32x4 zero = {0.f, 0.f, 0.f, 0.f};
    f32x4 acc[2][4];
    for (int s = 0; s < 6; ++s) {
        const int nc = s >> 1, kh = s & 1;
        const int bsel = s & 1;
        if (s < 5) {   // issue next sub-tile stage first
            int t = s + 1, nct = t >> 1, kht = t & 1;
            const u16* Bg = Wq + nct * 16384;
            #pragma unroll
            for (int i = tid; i < 1024; i += 256) {
                int kc = i >> 9, c = i & 511;
                async16(Bg + (size_t)(c >> 2) * 128 + (kht << 6) + (kc << 5) + ((c & 3) << 3),
                        Bb[t & 1] + (kc << 12) + (c << 3));
            }
        }
        if (kh == 0) {
            #pragma unroll
            for (int i = 0; i < 2; ++i)
                #pragma unroll
                for (int j = 0; j < 4; ++j) acc[i][j] = zero;
        }
        #pragma unroll
        for (int kc = 0; kc < 2; ++kc) {
            bf16x8 af[2], bfr[4];
            #pragma unroll
            for (int t = 0; t < 2; ++t)
                af[t] = *(const bf16x8*)(Ach + (2 * kh + kc) * CH_S + (wm + (t << 4) + lr) * ROW_S + (q << 3));
            #pragma unroll
            for (int t = 0; t < 4; ++t)
                bfr[t] = *(const bf16x8*)(Bb[bsel] + (kc << 12) + ((wn + (t << 4) + lr) << 5) + (q << 3));
            #pragma unroll
            for (int mt = 0; mt < 2; ++mt)
                #pragma unroll
                for (int nt = 0; nt < 4; ++nt)
                    acc[mt][nt] = __builtin_amdgcn_mfma_f32_16x16x32_bf16(
                        af[mt], bfr[nt], acc[mt][nt], 0, 0, 0);
        }
        if (kh == 1) {   // epilogue for this nc
            #pragma unroll
            for (int nt = 0; nt < 4; ++nt) {
                int col = wn + (nt << 4) + lr;
                float bv = BF(wtb[O_QKVB + d * 384 + nc * 128 + col]);
                #pragma unroll
                for (int mt = 0; mt < 2; ++mt) {
                    #pragma unroll
                    for (int i = 0; i < 4; ++i) {
                        int r = bm + wm + (mt << 4) + (q << 2) + i;
                        qkv[(size_t)r * 384 + nc * 128 + col] = FBu(acc[mt][nt][i] + bv);
                    }
                }
            }
        }
        if (s < 5) __syncthreads();   // drains stage(s+1); frees Bb[bsel]
    }
}

// ---------------------------------------------------------------------------
// Windowed MFMA attention + FUSED output projection. Block = one window;
// attn phase: wave = one head (wave-private LDS, no barriers). Then each
// wave writes its O columns (bf16, proj-A chunk layout, row stride 36) into
// its OWN pbuf slice (reuse after P consumed), ONE barrier, and the proj
// phase (wave = 32-col block) computes O @ pw + pb with window-reverse/roll
// scatter-add into g.
// ---------------------------------------------------------------------------
__launch_bounds__(256, 2)
__global__ void attn_k(const u16* __restrict__ qkv, const u16* __restrict__ wtu,
                       const bf16* __restrict__ wtb, float* __restrict__ g,
                       int d, int shift) {
    __shared__ __align__(16) u16 vT[4][32][72];    // V^T per head (padded)
    __shared__ __align__(16) u16 pbuf[4][4608];    // P bf16 / then O proj-A chunks
    const bf16* rp = wtb + O_RP + d * 900;
    const int wq = blockIdx.x;
    const int head = threadIdx.x >> 6;
    const int lane = threadIdx.x & 63;
    const int q8 = lane >> 4, lr = lane & 15;
    const size_t base = (size_t)wq * 64;
    const f32x4 zero = {0.f, 0.f, 0.f, 0.f};

    // stage V^T: thread=m-row, 4x bf16x8 global loads -> scattered u16 writes
    #pragma unroll
    for (int j = 0; j < 4; ++j) {
        bf16x8 vv = *(const bf16x8*)(qkv + (base + lane) * 384 + 256 + head * 32 + j * 8);
        #pragma unroll
        for (int e = 0; e < 8; ++e) vT[head][j * 8 + e][lane] = ((const u16*)&vv)[e];
    }

    // Q/K fragments direct from global (16B contiguous), S = Q K^T
    bf16x8 af[4], bfk[4];
    #pragma unroll
    for (int t = 0; t < 4; ++t) {
        af[t]  = *(const bf16x8*)(qkv + (base + t * 16 + lr) * 384 + head * 32 + q8 * 8);
        bfk[t] = *(const bf16x8*)(qkv + (base + t * 16 + lr) * 384 + 128 + head * 32 + q8 * 8);
    }
    f32x4 accs[4][4];
    #pragma unroll
    for (int rt = 0; rt < 4; ++rt)
        #pragma unroll
        for (int ct = 0; ct < 4; ++ct) accs[rt][ct] = zero;
    #pragma unroll
    for (int rt = 0; rt < 4; ++rt)
        #pragma unroll
        for (int ct = 0; ct < 4; ++ct)
            accs[rt][ct] = __builtin_amdgcn_mfma_f32_16x16x32_bf16(
                af[rt], bfk[ct], accs[rt][ct], 0, 0, 0);

    // scale + rel-pos bias + region mask + softmax + normalized bf16 P -> LDS
    const int wloc = wq & 63;
    const int wh = (wloc >> 3) << 3, wwb = (wloc & 7) << 3;
    #pragma unroll
    for (int rt = 0; rt < 4; ++rt) {
        #pragma unroll
        for (int i = 0; i < 4; ++i) {
            int r = rt * 16 + q8 * 4 + i;
            int ti = r >> 3, tj = r & 7;
            int regt = 0;
            if (shift) {
                int hp = wh + ti, wp = wwb + tj;
                int rh = hp < 56 ? 0 : (hp < 60 ? 1 : 2);
                int rw = wp < 56 ? 0 : (wp < 60 ? 1 : 2);
                regt = rh * 3 + rw;
            }
            float sv[4];
            float mx = -1e30f;
            #pragma unroll
            for (int ct = 0; ct < 4; ++ct) {
                int m = ct * 16 + lr;
                float a = accs[rt][ct][i] * 0.17677669529663687f;
                int idx = (ti - (m >> 3) + 7) * 15 + (tj - (m & 7) + 7);
                a += BF(rp[idx * 4 + head]);
                if (shift) {
                    int hp = wh + (m >> 3), wp = wwb + (m & 7);
                    int rh = hp < 56 ? 0 : (hp < 60 ? 1 : 2);
                    int rw = wp < 56 ? 0 : (wp < 60 ? 1 : 2);
                    if (regt != rh * 3 + rw) a -= 100.f;
                }
                sv[ct] = a;
                mx = fmaxf(mx, a);
            }
            mx = fmaxf(mx, __shfl_xor(mx, 1));
            mx = fmaxf(mx, __shfl_xor(mx, 2));
            mx = fmaxf(mx, __shfl_xor(mx, 4));
            mx = fmaxf(mx, __shfl_xor(mx, 8));
            float l = 0.f;
            #pragma unroll
            for (int ct = 0; ct < 4; ++ct) { sv[ct] = expf(sv[ct] - mx); l += sv[ct]; }
            l += __shfl_xor(l, 1); l += __shfl_xor(l, 2);
            l += __shfl_xor(l, 4); l += __shfl_xor(l, 8);
            float inv = 1.f / l;
            #pragma unroll
            for (int ct = 0; ct < 4; ++ct)
                pbuf[head][r * 72 + ct * 16 + lr] = FBu(sv[ct] * inv);
        }
    }

    // PV: O = P @ V  (A from pbuf rows, B from vT)
    f32x4 acco[4][2];
    #pragma unroll
    for (int rt = 0; rt < 4; ++rt) { acco[rt][0] = zero; acco[rt][1] = zero; }
    #pragma unroll
    for (int mh = 0; mh < 2; ++mh) {
        bf16x8 vb[2];
        #pragma unroll
        for (int dt = 0; dt < 2; ++dt)
            vb[dt] = *(const bf16x8*)(&vT[head][dt * 16 + lr][mh * 32 + q8 * 8]);
        #pragma unroll
        for (int rt = 0; rt < 4; ++rt) {
            bf16x8 pa = *(const bf16x8*)(&pbuf[head][(rt * 16 + lr) * 72 + mh * 32 + q8 * 8]);
            #pragma unroll
            for (int dt = 0; dt < 2; ++dt)
                acco[rt][dt] = __builtin_amdgcn_mfma_f32_16x16x32_bf16(
                    pa, vb[dt], acco[rt][dt], 0, 0, 0);
        }
    }

    // write O (bf16) into own pbuf slice as proj A-chunk: chunk=head holds
    // O cols [head*32, head*32+32), row stride 36 (bank-skewed, 16B-aligned)
    #pragma unroll
    for (int rt = 0; rt < 4; ++rt)
        #pragma unroll
        for (int dt = 0; dt < 2; ++dt)
            #pragma unroll
            for (int i = 0; i < 4; ++i) {
                int r = rt * 16 + q8 * 4 + i;
                pbuf[head][r * ROW_S + dt * 16 + lr] = FBu(acco[rt][dt][i]);
            }
    __syncthreads();

    // proj: C[64][128] = O @ pw^T + pb, scatter-add to g. wave = 32-col block.
    const u16* Wp = wtu + O_PW + d * 16384;
    const int wn = head << 5;
    f32x4 accp[4][2];
    #pragma unroll
    for (int rt = 0; rt < 4; ++rt) { accp[rt][0] = zero; accp[rt][1] = zero; }
    #pragma unroll
    for (int k0 = 0; k0 < 4; ++k0) {
        bf16x8 ap[4], bp[2];
        #pragma unroll
        for (int rt = 0; rt < 4; ++rt)
            ap[rt] = *(const bf16x8*)(&pbuf[k0][(rt * 16 + lr) * ROW_S + q8 * 8]);
        #pragma unroll
        for (int nt = 0; nt < 2; ++nt)
            bp[nt] = *(const bf16x8*)(Wp + (size_t)(wn + (nt << 4) + lr) * 128 + (k0 << 5) + (q8 << 3));
        #pragma unroll
        for (int rt = 0; rt < 4; ++rt)
            #pragma unroll
            for (int nt = 0; nt < 2; ++nt)
                accp[rt][nt] = __builtin_amdgcn_mfma_f32_16x16x32_bf16(
                    ap[rt], bp[nt], accp[rt][nt], 0, 0, 0);
    }
    #pragma unroll
    for (int nt = 0; nt < 2; ++nt) {
        int col = wn + (nt << 4) + lr;
        float bv = BF(wtb[O_PB + d * 128 + col]);
        #pragma unroll
        for (int rt = 0; rt < 4; ++rt) {
            #pragma unroll
            for (int i = 0; i < 4; ++i) {
                int r = (int)base + rt * 16 + q8 * 4 + i;
                float v = accp[rt][nt][i] + bv;
                int b = r >> 12, rem = r & 4095;
                int wi = rem >> 6, n = rem & 63;
                int hp = ((wi >> 3) << 3) + (n >> 3);
                int wp = ((wi & 7) << 3) + (n & 7);
                int h = (hp + shift) & 63, w = (wp + shift) & 63;
                g[((size_t)((b << 12) + (h << 6) + w)) * 128 + col] += v;
            }
        }
    }
}

// ---------------------------------------------------------------------------
// Fused MLP: LN2 + f1 + GELU + f2 + residual into g (+ optional bf16 copy
// to gbf; skipped for d=0 since d=1 overwrites it before fuse3 reads).
// Block = 64 rows, 512 blocks. Pipeline: stage B1(0) before LN; per h:
// issue B2(h), MFMA1+GELU, barrier, issue B1(h+1), MFMA2, barrier.
// ---------------------------------------------------------------------------
__launch_bounds__(256)
__global__ void mlp_k(float* __restrict__ g, bf16* __restrict__ gbf,
                      const u16* __restrict__ wtu, const bf16* __restrict__ wtb,
                      int d) {
    __shared__ __align__(16) u16 Ach[4 * CH_S];
    __shared__ __align__(16) u16 bufB1[8192];
    __shared__ __align__(16) u16 bufB2[8192];
    __shared__ __align__(16) u16 buf2[2 * CH_S];
    const int tid = threadIdx.x;
    const int wave = tid >> 6, lane = tid & 63;
    const int q = lane >> 4, lr = lane & 15;
    const int wm = (wave >> 1) << 5;   // 0 / 32 (row split)
    const int wn0 = (wave & 1) << 5;   // stage1: 32-hcol split
    const int wn = (wave & 1) << 6;    // stage2: 64-ncol split
    const int bm = blockIdx.x << 6;

    // prologue stage: B1 chunk h=0 (hides under LN's global loads)
    {
        const u16* B1g = wtu + O_F1W + d * 65536;
        #pragma unroll
        for (int i = tid; i < 1024; i += 256) {
            int kc = i >> 8, c = i & 255;
            async16(B1g + (c >> 2) * 128 + (kc << 5) + ((c & 3) << 3),
                    bufB1 + (kc << 11) + (c << 3));
        }
    }

    // LN2: thread = (row = tid>>2, qtr = tid&3)
    {
        int row = tid >> 2, qtr = tid & 3;
        const float* gr = g + (size_t)(bm + row) * 128 + qtr * 32;
        float vals[32];
        float s1 = 0.f, s2 = 0.f;
        #pragma unroll
        for (int i = 0; i < 8; ++i) {
            float4 v4 = *(const float4*)(gr + i * 4);
            vals[i * 4] = v4.x; vals[i * 4 + 1] = v4.y;
            vals[i * 4 + 2] = v4.z; vals[i * 4 + 3] = v4.w;
            s1 += v4.x + v4.y + v4.z + v4.w;
            s2 += v4.x * v4.x + v4.y * v4.y + v4.z * v4.z + v4.w * v4.w;
        }
        s1 += __shfl_xor(s1, 1); s1 += __shfl_xor(s1, 2);
        s2 += __shfl_xor(s2, 1); s2 += __shfl_xor(s2, 2);
        float mu = s1 * (1.f / 128.f);
        float var = s2 * (1.f / 128.f) - mu * mu;
        float inv = rsqrtf(var + 1e-5f);
        #pragma unroll
        for (int i = 0; i < 32; ++i) {
            int c = qtr * 32 + i;
            float o = (vals[i] - mu) * inv * BF(wtb[O_N2G + d * 128 + c])
                      + BF(wtb[O_N2B + d * 128 + c]);
            Ach[qtr * CH_S + row * ROW_S + i] = FBu(o);
        }
    }
    __syncthreads();   // drains B1(0); Ach visible

    const f32x4 zero = {0.f, 0.f, 0.f, 0.f};
    f32x4 acc2[2][4];
    #pragma unroll
    for (int i = 0; i < 2; ++i)
        #pragma unroll
        for (int j = 0; j < 4; ++j) acc2[i][j] = zero;

    for (int h = 0; h < 8; ++h) {
        // issue B2(h) stage first (hides under MFMA1 + GELU)
        {
            const u16* B2g = wtu + O_F2W + d * 65536 + h * 64;
            #pragma unroll
            for (int i = tid; i < 1024; i += 256) {
                int kc = i >> 9, c = i & 511;
                async16(B2g + (size_t)(c >> 2) * 512 + (kc << 5) + ((c & 3) << 3),
                        bufB2 + (kc << 12) + (c << 3));
            }
        }
        // MFMA1 from Ach x bufB1 (B1(h), ready from previous barrier)
        f32x4 acc1[2][2];
        #pragma unroll
        for (int i = 0; i < 2; ++i) { acc1[i][0] = zero; acc1[i][1] = zero; }
        #pragma unroll
        for (int k0 = 0; k0 < 4; ++k0) {
            bf16x8 af[2], bfr[2];
            #pragma unroll
            for (int t = 0; t < 2; ++t) {
                af[t]  = *(const bf16x8*)(Ach + k0 * CH_S + (wm + (t << 4) + lr) * ROW_S + (q << 3));
                bfr[t] = *(const bf16x8*)(bufB1 + (k0 << 11) + ((wn0 + (t << 4) + lr) << 5) + (q << 3));
            }
            #pragma unroll
            for (int mt = 0; mt < 2; ++mt)
                #pragma unroll
                for (int nt = 0; nt < 2; ++nt)
                    acc1[mt][nt] = __builtin_amdgcn_mfma_f32_16x16x32_bf16(
                        af[mt], bfr[nt], acc1[mt][nt], 0, 0, 0);
        }
        // GELU -> hidden chunks (padded) in buf2
        #pragma unroll
        for (int nt = 0; nt < 2; ++nt) {
            int c = wn0 + (nt << 4) + lr;
            float hb = BF(wtb[O_F1B + d * 512 + h * 64 + c]);
            #pragma unroll
            for (int mt = 0; mt < 2; ++mt) {
                #pragma unroll
                for (int i = 0; i < 4; ++i) {
                    int r = wm + (mt << 4) + (q << 2) + i;
                    float v = acc1[mt][nt][i] + hb;
                    float ge = 0.5f * v * (1.0f + erff(v * 0.70710678118654752f));
                    buf2[(c >> 5) * CH_S + r * ROW_S + (c & 31)] = FBu(ge);
                }
            }
        }
        __syncthreads();   // drains B2(h); buf2 visible; bufB1 free
        // issue B1(h+1) stage (hides under MFMA2)
        if (h < 7) {
            const u16* B1g = wtu + O_F1W + d * 65536 + (h + 1) * 8192;
            #pragma unroll
            for (int i = tid; i < 1024; i += 256) {
                int kc = i >> 8, c = i & 255;
                async16(B1g + (c >> 2) * 128 + (kc << 5) + ((c & 3) << 3),
                        bufB1 + (kc << 11) + (c << 3));
            }
        }
        // MFMA2 from buf2 x bufB2
        #pragma unroll
        for (int kc = 0; kc < 2; ++kc) {
            bf16x8 ah[2], b2[4];
            #pragma unroll
            for (int t = 0; t < 2; ++t)
                ah[t] = *(const bf16x8*)(buf2 + kc * CH_S + (wm + (t << 4) + lr) * ROW_S + (q << 3));
            #pragma unroll
            for (int t = 0; t < 4; ++t)
                b2[t] = *(const bf16x8*)(bufB2 + (kc << 12) + ((wn + (t << 4) + lr) << 5) + (q << 3));
            #pragma unroll
            for (int mt = 0; mt < 2; ++mt)
                #pragma unroll
                for (int nt = 0; nt < 4; ++nt)
                    acc2[mt][nt] = __builtin_amdgcn_mfma_f32_16x16x32_bf16(
                        ah[mt], b2[nt], acc2[mt][nt], 0, 0, 0);
        }
        __syncthreads();   // drains B1(h+1); bufB2/buf2 free
    }
    #pragma unroll
    for (int nt = 0; nt < 4; ++nt) {
        int col = wn + (nt << 4) + lr;
        float bv = BF(wtb[O_F2B + d * 128 + col]);
        #pragma unroll
        for (int mt = 0; mt < 2; ++mt) {
            #pragma unroll
            for (int i = 0; i < 4; ++i) {
                int r = bm + wm + (mt << 4) + (q << 2) + i;
                size_t idx = (size_t)r * 128 + col;
                float nv = g[idx] + acc2[mt][nt][i] + bv;
                g[idx] = nv;
                if (gbf) gbf[idx] = FB(nv);
            }
        }
    }
}

// ---------------------------------------------------------------------------
// Fused fusion chain + LSTM gate -> out. 32-row tiles, 1024 blocks
// (4 blocks/CU). GEMM operands direct from global; ReLU intermediate in
// padded LDS (4 chunks of [32][36], +16 skew). 1 barrier total.
// ---------------------------------------------------------------------------
__launch_bounds__(256, 4)
__global__ void fuse3_k(const u16* __restrict__ Aloc, const u16* __restrict__ Ag,
                        const u16* __restrict__ wtu, const bf16* __restrict__ wtb,
                        const void* __restrict__ cx, void* __restrict__ out,
                        const void* __restrict__ dtp) {
    __shared__ __align__(16) u16 relb[4 * CH32_S];
    const int mode = get_mode(dtp);
    const int tid = threadIdx.x;
    const int wave = tid >> 6, lane = tid & 63;
    const int q = lane >> 4, lr = lane & 15;
    const int wn = wave << 5;          // 4 waves x 32-col split
    const int bm = blockIdx.x << 5;    // 32-row tile
    const f32x4 zero = {0.f, 0.f, 0.f, 0.f};
    f32x4 acc1[2][2], acc2[2][2];
    #pragma unroll
    for (int i = 0; i < 2; ++i)
        #pragma unroll
        for (int j = 0; j < 2; ++j) { acc1[i][j] = zero; acc2[i][j] = zero; }

    #pragma unroll
    for (int k0 = 0; k0 < 4; ++k0) {
        bf16x8 al[2], ag[2], blf[2], bgf[2];
        #pragma unroll
        for (int t = 0; t < 2; ++t) {
            size_t off = (size_t)(bm + (t << 4) + lr) * 128 + (k0 << 5) + (q << 3);
            al[t] = *(const bf16x8*)(Aloc + off);
            ag[t] = *(const bf16x8*)(Ag + off);
        }
        #pragma unroll
        for (int t = 0; t < 2; ++t) {
            int woff = ((wn + (t << 4) + lr) << 7) + (k0 << 5) + (q << 3);
            blf[t] = *(const bf16x8*)(wtu + O_LFW + woff);
            bgf[t] = *(const bf16x8*)(wtu + O_GFW + woff);
        }
        #pragma unroll
        for (int mt = 0; mt < 2; ++mt)
            #pragma unroll
            for (int nt = 0; nt < 2; ++nt) {
                acc1[mt][nt] = __builtin_amdgcn_mfma_f32_16x16x32_bf16(
                    al[mt], blf[nt], acc1[mt][nt], 0, 0, 0);
                acc2[mt][nt] = __builtin_amdgcn_mfma_f32_16x16x32_bf16(
                    ag[mt], bgf[nt], acc2[mt][nt], 0, 0, 0);
            }
    }
    // relu((local@lf + lfb) * (g@gf + gfb)) -> padded LDS (chunk = wave)
    #pragma unroll
    for (int nt = 0; nt < 2; ++nt) {
        int c = wn + (nt << 4) + lr;
        float lfb = BF(wtb[O_LFB + c]);
        float gfb = BF(wtb[O_GFB + c]);
        #pragma unroll
        for (int mt = 0; mt < 2; ++mt) {
            #pragma unroll
            for (int i = 0; i < 4; ++i) {
                int r = (mt << 4) + (q << 2) + i;
                float t1 = acc1[mt][nt][i] + lfb;
                float t2 = acc2[mt][nt][i] + gfb;
                float rel = t1 * t2;
                relb[(c >> 5) * CH32_S + r * ROW_S + (c & 31)] = FBu(rel > 0.f ? rel : 0.f);
            }
        }
    }
    __syncthreads();
    f32x4 acc3[2][2];
    #pragma unroll
    for (int i = 0; i < 2; ++i)
        #pragma unroll
        for (int j = 0; j < 2; ++j) acc3[i][j] = zero;
    #pragma unroll
    for (int k0 = 0; k0 < 4; ++k0) {
        bf16x8 ar[2], bff[2];
        #pragma unroll
        for (int t = 0; t < 2; ++t)
            ar[t] = *(const bf16x8*)(relb + k0 * CH32_S + ((t << 4) + lr) * ROW_S + (q << 3));
        #pragma unroll
        for (int t = 0; t < 2; ++t)
            bff[t] = *(const bf16x8*)(wtu + O_FFW + ((wn + (t << 4) + lr) << 7) + (k0 << 5) + (q << 3));
        #pragma unroll
        for (int mt = 0; mt < 2; ++mt)
            #pragma unroll
            for (int nt = 0; nt < 2; ++nt)
                acc3[mt][nt] = __builtin_amdgcn_mfma_f32_16x16x32_bf16(
                    ar[mt], bff[nt], acc3[mt][nt], 0, 0, 0);
    }
    // LSTM gating epilogue
    #pragma unroll
    for (int nt = 0; nt < 2; ++nt) {
        int col = wn + (nt << 4) + lr;
        float ffb = BF(wtb[O_FFB + col]);
        #pragma unroll
        for (int mt = 0; mt < 2; ++mt) {
            #pragma unroll
            for (int i = 0; i < 4; ++i) {
                int r = bm + (mt << 4) + (q << 2) + i;
                size_t idx = (size_t)r * 128 + col;
                float v = acc3[mt][nt][i] + ffb;
                float gate = 1.f / (1.f + expf(-v));
                float cell = tanhf(v);
                float cy = gate * (LD(cx, idx, mode) + cell);
                float hy = gate * tanhf(cy);
                if (mode) ((float*)out)[idx] = hy;
                else      ((bf16*)out)[idx] = FB(hy);
            }
        }
    }
}

// ---------------------------------------------------------------------------
// Deformable conv1d, stage 1: offset/mask conv. One WAVE per output position.
// ---------------------------------------------------------------------------
__launch_bounds__(256)
__global__ void offmask_k(const void* __restrict__ xt, const bf16* __restrict__ wtb,
                          float4* __restrict__ om) {
    const int mode = get_mode(xt);
    const int wave = threadIdx.x >> 6, lane = threadIdx.x & 63;
    const int gl = blockIdx.x * 4 + wave;
    const int b = gl >> 12, l = gl & 4095;
    float wo[3][3][2], wmk[3][3][2];
    #pragma unroll
    for (int k = 0; k < 3; ++k)
        #pragma unroll
        for (int j = 0; j < 3; ++j) {
            wo[k][j][0]  = BF(wtb[O_OW + (k * 128 + lane) * 3 + j]);
            wo[k][j][1]  = BF(wtb[O_OW + (k * 128 + lane + 64) * 3 + j]);
            wmk[k][j][0] = BF(wtb[O_MW + (k * 128 + lane) * 3 + j]);
            wmk[k][j][1] = BF(wtb[O_MW + (k * 128 + lane + 64) * 3 + j]);
        }
    float a6[6] = {};
    #pragma unroll
    for (int j = 0; j < 3; ++j) {
        int row = l + j - 1;
        if (row >= 0 && row < 4096) {
            size_t base = ((size_t)(b << 12) + row) * 128;
            float x0 = LD(xt, base + lane, mode);
            float x1 = LD(xt, base + lane + 64, mode);
            #pragma unroll
            for (int k = 0; k < 3; ++k) {
                a6[k]     += x0 * wo[k][j][0]  + x1 * wo[k][j][1];
                a6[3 + k] += x0 * wmk[k][j][0] + x1 * wmk[k][j][1];
            }
        }
    }
    #pragma unroll
    for (int off = 32; off > 0; off >>= 1)
        #pragma unroll
        for (int k = 0; k < 6; ++k) a6[k] += __shfl_down(a6[k], off);
    if (lane == 0) {
        #pragma unroll
        for (int k = 0; k < 3; ++k) {
            float off = a6[k] + BF(wtb[O_OB + k]);
            float pos = fminf(fmaxf((float)l + off, 0.f), 4095.f);
            float fpf = floorf(pos);
            float mv = a6[3 + k] + BF(wtb[O_MB + k]);
            float mk = 1.f / (1.f + expf(-mv));
            om[(size_t)gl * 3 + k] = make_float4(fpf, pos - fpf, mk, 0.f);
        }
    }
}

// ---------------------------------------------------------------------------
// Deformable conv1d, stage 2: sampling + transpose to (B,C,L) bf16.
// ---------------------------------------------------------------------------
__launch_bounds__(512)
__global__ void sample_k(const void* __restrict__ xt, const float4* __restrict__ om,
                         bf16* __restrict__ outL) {
    __shared__ __align__(16) u16 ot[128 * 72];
    const int mode = get_mode(xt);
    const int tid = threadIdx.x;
    const int b = blockIdx.x >> 6;
    const int l0 = (blockIdx.x & 63) << 6;
    const int c = tid & 127, lh = tid >> 7;
    for (int it = 0; it < 16; ++it) {
        int l_loc = lh * 16 + it;
        size_t gl = (size_t)(b << 12) + l0 + l_loc;
        float o = 0.f;
        #pragma unroll
        for (int k = 0; k < 3; ++k) {
            float4 v = om[gl * 3 + k];
            int fp = (int)v.x;
            int cp = fp + 1 > 4095 ? 4095 : fp + 1;
            float al = v.y, mk = v.z;
            float xf = LD(xt, ((size_t)(b << 12) + fp) * 128 + c, mode);
            float xc = LD(xt, ((size_t)(b << 12) + cp) * 128 + c, mode);
            o += (xf * (1.f - al) + xc * al) * mk;
        }
        ot[c * 72 + l_loc] = FBu(o);
    }
    __syncthreads();
    #pragma unroll
    for (int pass = 0; pass < 2; ++pass) {
        int cc = pass * 64 + (tid >> 3);
        int oo = tid & 7;
        const uint4 v = *(const uint4*)(ot + cc * 72 + oo * 8);
        *(uint4*)(outL + (size_t)b * 524288 + (size_t)cc * 4096 + l0 + oo * 8) = v;
    }
}

extern "C" void kernel_launch(void* const* d_in, const int* in_sizes, int n_in,
                              void* d_out, int out_size, void* d_ws, size_t ws_size,
                              hipStream_t stream) {
    (void)out_size; (void)ws_size;
    int I[28] = {0,1,2,3,4,5,6,7,8,9,10,11,12,13,14,15,16,17,18,19,20,21,22,23,24,25,26,27};
    if (n_in >= 28 && in_sizes[7] != 98304 && in_sizes[23] == 98304 && in_sizes[26] == 1800) {
        int alt[28] = {27, 9, 0, 25, 24, 15, 14, 23, 22, 26, 21, 20, 17, 16,
                       2, 1, 4, 3, 19, 18, 13, 12, 11, 10, 8, 7, 6, 5};
        for (int i = 0; i < 28; ++i) I[i] = alt[i];
    }
    const void* xt = d_in[I[0]];
    const void* hx = d_in[I[1]];
    const void* cx = d_in[I[2]];

    char* wsb = (char*)d_ws;
    float* g    = (float*)wsb;                    // fp32 residual [0,16M)
    u16*   Abf  = (u16*)(wsb + 16777216);         // bf16(g)
    u16*   Bbf  = (u16*)(wsb + 25165824);         // qkv
    u16*   Cbf  = (u16*)(wsb + 50331648);         // local branch
    bf16*  wtb  = (bf16*)(wsb + 58720256);
    u16*   wtu  = (u16*)wtb;
    float4* om  = (float4*)(wsb + 25165824);      // reuses Bbf after last attn

    Prep p;
    PrepT descs[29] = {
        {d_in[I[3]],  0,     256, 128, O_REDW},
        {d_in[I[7]],  0,     128, 384, O_QKVW},
        {d_in[I[7]],  49152, 128, 384, O_QKVW + 49152},
        {d_in[I[10]], 0,     128, 128, O_PW},
        {d_in[I[10]], 16384, 128, 128, O_PW + 16384},
        {d_in[I[14]], 0,     128, 512, O_F1W},
        {d_in[I[14]], 65536, 128, 512, O_F1W + 65536},
        {d_in[I[16]], 0,     512, 128, O_F2W},
        {d_in[I[16]], 65536, 512, 128, O_F2W + 65536},
        {d_in[I[22]], 0,     128, 128, O_LFW},
        {d_in[I[24]], 0,     128, 128, O_GFW},
        {d_in[I[26]], 0,     128, 128, O_FFW},
        {d_in[I[4]],  0,  128, 0, O_REDB},
        {d_in[I[8]],  0,  768, 0, O_QKVB},
        {d_in[I[11]], 0,  256, 0, O_PB},
        {d_in[I[15]], 0, 1024, 0, O_F1B},
        {d_in[I[17]], 0,  256, 0, O_F2B},
        {d_in[I[23]], 0,  128, 0, O_LFB},
        {d_in[I[25]], 0,  128, 0, O_GFB},
        {d_in[I[27]], 0,  128, 0, O_FFB},
        {d_in[I[9]],  0, 1800, 0, O_RP},
        {d_in[I[5]],  0,  256, 0, O_N1G},
        {d_in[I[6]],  0,  256, 0, O_N1B},
        {d_in[I[12]], 0,  256, 0, O_N2G},
        {d_in[I[13]], 0,  256, 0, O_N2B},
        {d_in[I[18]], 0, 1152, 0, O_OW},
        {d_in[I[19]], 0,    3, 0, O_OB},
        {d_in[I[20]], 0, 1152, 0, O_MW},
        {d_in[I[21]], 0,    3, 0, O_MB},
    };
    int cum = 0;
    for (int i = 0; i < 29; ++i) {
        p.d[i] = descs[i];
        p.start[i] = cum;
        cum += (descs[i].N > 0) ? descs[i].K * descs[i].N : descs[i].K;
    }
    p.start[29] = cum;

    prep_k<<<(cum + 255) / 256, 256, 0, stream>>>(p, wtb, xt);

    // g = [xt|hx] @ red_w + red_b (fp32), concat fused into A staging
    redgemm_k<<<512, 256, 0, stream>>>(xt, hx, wtu + O_REDW, wtb + O_REDB, g);

    for (int d = 0; d < 2; ++d) {
        int shift = d ? 4 : 0;
        qkvln_k<<<512, 256, 0, stream>>>(g, wtu, wtb, Bbf, d, shift);
        attn_k<<<512, 256, 0, stream>>>(Bbf, wtu, wtb, g, d, shift);
        mlp_k<<<512, 256, 0, stream>>>(g, d ? (bf16*)Abf : nullptr, wtu, wtb, d);
    }

    // local branch: offset/mask conv (wave-per-l), then sampling -> Cbf (B,C,L)
    offmask_k<<<8192, 256, 0, stream>>>(xt, wtb, om);
    sample_k<<<512, 512, 0, stream>>>(xt, om, (bf16*)Cbf);
    // fused fusion chain + LSTM -> out
    fuse3_k<<<1024, 256, 0, stream>>>(Cbf, Abf, wtu, wtb, cx, d_out, xt);
}